// Round 3
// baseline (2808.963 us; speedup 1.0000x reference)
//
#include <hip/hip_runtime.h>

typedef unsigned short u16;

__device__ __forceinline__ float bf2f(u16 u) {
    return __uint_as_float(((unsigned int)u) << 16);
}
__device__ __forceinline__ u16 f2bf(float f) {
    unsigned int x = __float_as_uint(f);
    return (u16)((x + 0x7fffu + ((x >> 16) & 1u)) >> 16);
}
__device__ __forceinline__ float lrelu(float x) { return x >= 0.f ? x : 0.01f * x; }
__device__ __forceinline__ float eluf(float x)  { return x > 0.f ? x : expm1f(x); }

// dual-dtype scalar load: f32 ? float : bf16
__device__ __forceinline__ float ldv(const void* p, size_t i, int f32) {
    return f32 ? ((const float*)p)[i] : bf2f(((const u16*)p)[i]);
}
__device__ __forceinline__ void stv(void* p, int i, float v, int f32) {
    if (f32) ((float*)p)[i] = v;
    else ((u16*)p)[i] = f2bf(v);
}
// load 8 consecutive weights starting at element i8*8
__device__ __forceinline__ void load_w8d(const void* p, size_t i8, int f32, float* wr) {
    if (f32) {
        const float4* q = reinterpret_cast<const float4*>((const float*)p + i8 * 8);
        float4 a = q[0], b = q[1];
        wr[0] = a.x; wr[1] = a.y; wr[2] = a.z; wr[3] = a.w;
        wr[4] = b.x; wr[5] = b.y; wr[6] = b.z; wr[7] = b.w;
    } else {
        const u16* wp = (const u16*)p + i8 * 8;
        uint4 wq = *reinterpret_cast<const uint4*>(wp);
        wr[0] = bf2f((u16)(wq.x & 0xffff)); wr[1] = bf2f((u16)(wq.x >> 16));
        wr[2] = bf2f((u16)(wq.y & 0xffff)); wr[3] = bf2f((u16)(wq.y >> 16));
        wr[4] = bf2f((u16)(wq.z & 0xffff)); wr[5] = bf2f((u16)(wq.z >> 16));
        wr[6] = bf2f((u16)(wq.w & 0xffff)); wr[7] = bf2f((u16)(wq.w >> 16));
    }
}

// sparsemax over 16 elements (Martins & Astudillo), exact ksup-count semantics
__device__ void sparsemax16(const float* z, float* out) {
    float zs[16];
    for (int i = 0; i < 16; ++i) zs[i] = z[i];
    for (int i = 1; i < 16; ++i) {
        float key = zs[i]; int j = i - 1;
        while (j >= 0 && zs[j] < key) { zs[j + 1] = zs[j]; --j; }
        zs[j + 1] = key;
    }
    float cum[16];
    cum[0] = zs[0];
    for (int i = 1; i < 16; ++i) cum[i] = cum[i - 1] + zs[i];
    int ksup = 0;
    for (int k = 1; k <= 16; ++k)
        if (1.0f + (float)k * zs[k - 1] > cum[k - 1]) ksup++;
    if (ksup < 1) ksup = 1;
    float tau = (cum[ksup - 1] - 1.0f) / (float)ksup;
    for (int i = 0; i < 16; ++i) out[i] = fmaxf(z[i] - tau, 0.0f);
}

// ---- dtype probe: bf16 data has no inf/NaN patterns; fp32-as-u16 has ~1000 --
__global__ __launch_bounds__(256) void k_probe(const u16* __restrict__ x, int n,
                                               int* __restrict__ flag) {
    __shared__ int cnt;
    if (threadIdx.x == 0) cnt = 0;
    __syncthreads();
    int local = 0;
    for (int i = threadIdx.x; i < n; i += 256) {
        u16 u = x[i];
        if ((u & 0x7F80) == 0x7F80) local = 1;
    }
    if (local) atomicOr(&cnt, 1);
    __syncthreads();
    if (threadIdx.x == 0) *flag = cnt;   // 1 => inputs are float32
}

// ===== fused CNN: conv1+bn+relu+pool -> conv2 -> conv3 -> mean  rep[8,256,128]
__global__ __launch_bounds__(256) void k_cnn(
    const void* __restrict__ x,
    const void* __restrict__ w1, const void* __restrict__ g1, const void* __restrict__ b1,
    const void* __restrict__ m1, const void* __restrict__ v1,
    const void* __restrict__ w2, const void* __restrict__ g2, const void* __restrict__ b2,
    const void* __restrict__ m2, const void* __restrict__ v2,
    const void* __restrict__ w3, const void* __restrict__ g3, const void* __restrict__ b3,
    const void* __restrict__ m3, const void* __restrict__ v3,
    const int* __restrict__ flagp, float* __restrict__ rep)
{
    __shared__ float xin[264];        // conv1 input, data at +4, len 256
    __shared__ float s1[32][137];     // pool1, data at [ci][4+p], p in [0,128]
    __shared__ float s2[64][74];      // pool2, data at [ci][4+p], p in [0,65]
    __shared__ float partial[128][9];

    int f32 = *flagp;
    int tid = threadIdx.x, blk = blockIdx.x;
    int f = blk >> 8, n = blk & 255, bb = n >> 4, ss = n & 15;

    for (int i = tid; i < 264; i += 256) xin[i] = 0.f;
    {
        float* p1 = &s1[0][0];
        for (int i = tid; i < 32 * 137; i += 256) p1[i] = 0.f;
        float* p2 = &s2[0][0];
        for (int i = tid; i < 64 * 74; i += 256) p2[i] = 0.f;
    }
    __syncthreads();
    size_t xoff = (((size_t)bb * 8 + f) * 16 + ss) * 256;
    for (int i = tid; i < 256; i += 256) xin[i + 4] = ldv(x, xoff + i, f32);
    __syncthreads();

    // ---- conv1 (1->32, 256 -> conv 257 -> pool 129) ----
    for (int tt = tid; tt < 264; tt += 256) {
        int cc = tt & 7, jc = tt >> 3;
        int co0 = cc * 4, j0 = jc * 4;
        float wr[4][8];
        for (int c = 0; c < 4; ++c) load_w8d(w1, (size_t)f * 32 + co0 + c, f32, wr[c]);
        int px[8];
        for (int i = 0; i < 8; ++i) {
            int p = 2 * j0 - 1 + i;
            px[i] = p < 0 ? 0 : (p > 256 ? 256 : p);
        }
        float acc[4][8];
        for (int c = 0; c < 4; ++c) for (int i = 0; i < 8; ++i) acc[c][i] = 0.f;
        for (int k = 0; k < 8; ++k) {
            float xv[8];
            for (int i = 0; i < 8; ++i) xv[i] = xin[px[i] + k];
            for (int c = 0; c < 4; ++c)
                for (int i = 0; i < 8; ++i) acc[c][i] += wr[c][k] * xv[i];
        }
        for (int c = 0; c < 4; ++c) {
            int co = co0 + c;
            float sc = ldv(g1, f * 32 + co, f32) * rsqrtf(ldv(v1, f * 32 + co, f32) + 1e-5f);
            float sh = ldv(b1, f * 32 + co, f32) - ldv(m1, f * 32 + co, f32) * sc;
            for (int jj = 0; jj < 4; ++jj) {
                int j = j0 + jj;
                if (j < 129) {
                    float a0 = fmaxf(acc[c][2 * jj] * sc + sh, 0.f);
                    float a1 = fmaxf(acc[c][2 * jj + 1] * sc + sh, 0.f);
                    s1[co][4 + j] = fmaxf(a0, a1);
                }
            }
        }
    }
    __syncthreads();

    // ---- conv2 (32->64, 129 -> conv 130 -> pool 66) ----
    for (int tt = tid; tt < 272; tt += 256) {
        int cc = tt & 15, jc = tt >> 4;
        int co0 = cc * 4, j0 = jc * 4;
        int px[8];
        for (int i = 0; i < 8; ++i) {
            int p = 2 * j0 - 1 + i;
            px[i] = p < 0 ? 0 : (p > 129 ? 129 : p);
        }
        float acc[4][8];
        for (int c = 0; c < 4; ++c) for (int i = 0; i < 8; ++i) acc[c][i] = 0.f;
        for (int ci = 0; ci < 32; ++ci) {
            float wr[4][8];
            for (int c = 0; c < 4; ++c)
                load_w8d(w2, ((size_t)f * 64 + co0 + c) * 32 + ci, f32, wr[c]);
            for (int k = 0; k < 8; ++k) {
                float xv[8];
                for (int i = 0; i < 8; ++i) xv[i] = s1[ci][px[i] + k];
                for (int c = 0; c < 4; ++c)
                    for (int i = 0; i < 8; ++i) acc[c][i] += wr[c][k] * xv[i];
            }
        }
        for (int c = 0; c < 4; ++c) {
            int co = co0 + c;
            float sc = ldv(g2, f * 64 + co, f32) * rsqrtf(ldv(v2, f * 64 + co, f32) + 1e-5f);
            float sh = ldv(b2, f * 64 + co, f32) - ldv(m2, f * 64 + co, f32) * sc;
            for (int jj = 0; jj < 4; ++jj) {
                int j = j0 + jj;
                if (j < 66) {
                    float a0 = fmaxf(acc[c][2 * jj] * sc + sh, 0.f);
                    float a1 = fmaxf(acc[c][2 * jj + 1] * sc + sh, 0.f);
                    s2[co][4 + j] = fmaxf(a0, a1);
                }
            }
        }
    }
    __syncthreads();

    // ---- conv3 (64->128, 66 -> conv 67 -> pool 34 -> mean) ----
    for (int tt = tid; tt < 288; tt += 256) {
        int cc = tt & 31, jc = tt >> 5;
        int co0 = cc * 4, j0 = jc * 4;
        int px[8];
        for (int i = 0; i < 8; ++i) {
            int p = 2 * j0 - 1 + i;
            px[i] = p < 0 ? 0 : (p > 66 ? 66 : p);
        }
        float acc[4][8];
        for (int c = 0; c < 4; ++c) for (int i = 0; i < 8; ++i) acc[c][i] = 0.f;
        for (int ci = 0; ci < 64; ++ci) {
            float wr[4][8];
            for (int c = 0; c < 4; ++c)
                load_w8d(w3, ((size_t)f * 128 + co0 + c) * 64 + ci, f32, wr[c]);
            for (int k = 0; k < 8; ++k) {
                float xv[8];
                for (int i = 0; i < 8; ++i) xv[i] = s2[ci][px[i] + k];
                for (int c = 0; c < 4; ++c)
                    for (int i = 0; i < 8; ++i) acc[c][i] += wr[c][k] * xv[i];
            }
        }
        for (int c = 0; c < 4; ++c) {
            int co = co0 + c;
            float sc = ldv(g3, f * 128 + co, f32) * rsqrtf(ldv(v3, f * 128 + co, f32) + 1e-5f);
            float sh = ldv(b3, f * 128 + co, f32) - ldv(m3, f * 128 + co, f32) * sc;
            float sum = 0.f;
            for (int jj = 0; jj < 4; ++jj) {
                int j = j0 + jj;
                if (j < 34) {
                    float a0 = fmaxf(acc[c][2 * jj] * sc + sh, 0.f);
                    float a1 = fmaxf(acc[c][2 * jj + 1] * sc + sh, 0.f);
                    sum += fmaxf(a0, a1);
                }
            }
            partial[co][jc] = sum;
        }
    }
    __syncthreads();
    if (tid < 128) {
        float s = 0.f;
        for (int jc = 0; jc < 9; ++jc) s += partial[tid][jc];
        rep[(((size_t)f * 256) + n) * 128 + tid] = s * (1.0f / 34.0f);
    }
}

// ---- QKV + scores + intra sparsemax + Z(normalized) + rep inv-norms --------
__global__ __launch_bounds__(128) void k_attn1(
    const float* __restrict__ rep,
    const void* __restrict__ Wq, const void* __restrict__ bq,
    const void* __restrict__ Wk, const void* __restrict__ bk,
    const void* __restrict__ Wv, const void* __restrict__ bv,
    const int* __restrict__ flagp,
    float* __restrict__ Zn, float* __restrict__ rninv, float* __restrict__ iaw)
{
    __shared__ float repL[2048], QL[2048], VL[2048];
    __shared__ float KmL[128], red[128], scoresL[16], awL[16];
    int f32 = *flagp;
    int tid = threadIdx.x;
    int f = blockIdx.x >> 4, b = blockIdx.x & 15;
    const float* rb = rep + ((size_t)f * 256 + b * 16) * 128;
    for (int i = tid; i < 2048; i += 128) repL[i] = rb[i];
    __syncthreads();

    int h2 = tid;
    float km = 0.f;
    float bqv = ldv(bq, h2, f32), bkv = ldv(bk, h2, f32), bvv = ldv(bv, h2, f32);
    for (int s0 = 0; s0 < 16; s0 += 8) {
        float aq[8], ak[8], av[8];
        for (int t = 0; t < 8; ++t) { aq[t] = bqv; ak[t] = bkv; av[t] = bvv; }
        for (int h = 0; h < 128; ++h) {
            float wq = ldv(Wq, h * 128 + h2, f32);
            float wk = ldv(Wk, h * 128 + h2, f32);
            float wv = ldv(Wv, h * 128 + h2, f32);
            for (int t = 0; t < 8; ++t) {
                float r = repL[(s0 + t) * 128 + h];
                aq[t] += r * wq; ak[t] += r * wk; av[t] += r * wv;
            }
        }
        for (int t = 0; t < 8; ++t) {
            QL[(s0 + t) * 128 + h2] = eluf(aq[t]);
            VL[(s0 + t) * 128 + h2] = lrelu(av[t]);
            km += lrelu(ak[t]);
        }
    }
    KmL[h2] = km * (1.f / 16.f);
    __syncthreads();

    if (tid < 16) {
        float a = 0.f;
        for (int h = 0; h < 128; ++h) a += QL[tid * 128 + h] * KmL[h];
        scoresL[tid] = a * 0.08838834764831845f;   // 1/sqrt(128)
        float r2 = 0.f;
        for (int h = 0; h < 128; ++h) { float r = repL[tid * 128 + h]; r2 += r * r; }
        rninv[f * 256 + b * 16 + tid] = 1.f / fmaxf(sqrtf(r2), 1e-12f);
    }
    __syncthreads();
    if (tid == 0) sparsemax16(scoresL, awL);
    __syncthreads();
    if (tid < 16) iaw[f * 256 + b * 16 + tid] = awL[tid];

    float z = 0.f;
    for (int s = 0; s < 16; ++s) z += awL[s] * VL[s * 128 + tid];
    red[tid] = z * z;
    __syncthreads();
    for (int st = 64; st > 0; st >>= 1) {
        if (tid < st) red[tid] += red[tid + st];
        __syncthreads();
    }
    float inv = 1.f / fmaxf(sqrtf(red[0]), 1e-12f);
    Zn[((size_t)f * 16 + b) * 128 + tid] = z * inv;
}

// ---- inter scores + sparsemax + U + Hc + BN(feat) --------------------------
__global__ __launch_bounds__(256) void k_attn2(
    const float* __restrict__ rep, const float* __restrict__ Zn,
    const float* __restrict__ rninv, float* __restrict__ ibw,
    const void* __restrict__ g, const void* __restrict__ bb,
    const void* __restrict__ mm, const void* __restrict__ vv,
    const int* __restrict__ flagp,
    float* __restrict__ featbn, int write_feat)
{
    __shared__ float ZnL[1024], sc[1024], UL[1024], nrm[8];
    int f32 = *flagp;
    int tid = threadIdx.x, b = blockIdx.x;
    for (int i = tid; i < 1024; i += 256) {
        int ii = i >> 7, h = i & 127;
        ZnL[i] = Zn[((size_t)ii * 16 + b) * 128 + h];
    }
    if (tid < 8) nrm[tid] = 0.f;
    __syncthreads();

    for (int e = tid; e < 1024; e += 256) {
        int i = e >> 7, f = (e >> 4) & 7, s = e & 15;
        const float* rr = rep + ((size_t)f * 256 + b * 16 + s) * 128;
        float a = 0.f;
        for (int h = 0; h < 128; ++h) a += ZnL[i * 128 + h] * rr[h];
        sc[(i * 8 + f) * 16 + s] = a * rninv[f * 256 + b * 16 + s];
    }
    __syncthreads();
    if (tid < 64) {
        int i = tid >> 3, f = tid & 7;
        float aw[16];
        sparsemax16(&sc[(i * 8 + f) * 16], aw);
        for (int s = 0; s < 16; ++s) {
            sc[(i * 8 + f) * 16 + s] = aw[s];
            ibw[(((size_t)i * 8 + f) * 16 + b) * 16 + s] = aw[s];
        }
    }
    __syncthreads();
    for (int e = tid; e < 1024; e += 256) {
        int i = e >> 7, h = e & 127;
        float u = 0.f;
        for (int f = 0; f < 8; ++f) {
            const float* rr = rep + ((size_t)f * 256 + b * 16) * 128 + h;
            const float* aa = &sc[(i * 8 + f) * 16];
            for (int s = 0; s < 16; ++s) u += aa[s] * rr[s * 128];
        }
        UL[e] = u * 0.125f;
    }
    __syncthreads();
    if (write_feat) {
        for (int e = tid; e < 1024; e += 256) {
            int f = e >> 7;
            float zz = ZnL[e], uu = UL[e];
            atomicAdd(&nrm[f], zz * zz + uu * uu);
        }
        __syncthreads();
        for (int e = tid; e < 2048; e += 256) {
            int f = e >> 8, d = e & 255;
            float inv = 1.f / fmaxf(sqrtf(nrm[f]), 1e-12f);
            float val = (d < 128 ? ZnL[f * 128 + d] : UL[f * 128 + d - 128]) * inv;
            float scv = ldv(g, e, f32) * rsqrtf(ldv(vv, e, f32) + 1e-5f);
            featbn[b * 2048 + e] = (val - ldv(mm, e, f32)) * scv + ldv(bb, e, f32);
        }
    }
}

// ---- dense head: bn(feat)@W1+b1, bn2, leaky, @W2+b2, softmax ---------------
__global__ __launch_bounds__(256) void k_head(
    const float* __restrict__ featbn,
    const void* __restrict__ W1, const void* __restrict__ b1,
    const void* __restrict__ g2, const void* __restrict__ bb2,
    const void* __restrict__ mm2, const void* __restrict__ vv2,
    const void* __restrict__ W2, const void* __restrict__ b2,
    const int* __restrict__ flagp,
    float* __restrict__ ypred, void* __restrict__ dout)
{
    __shared__ float featL[2048], h2L[512], lgL[10];
    int f32 = *flagp;
    int tid = threadIdx.x, b = blockIdx.x;
    for (int i = tid; i < 2048; i += 256) featL[i] = featbn[b * 2048 + i];
    __syncthreads();
    for (int col = tid; col < 512; col += 256) {
        float a = ldv(b1, col, f32);
        for (int c = 0; c < 2048; ++c) a += featL[c] * ldv(W1, (size_t)c * 512 + col, f32);
        float scv = ldv(g2, col, f32) * rsqrtf(ldv(vv2, col, f32) + 1e-5f);
        float val = (a - ldv(mm2, col, f32)) * scv + ldv(bb2, col, f32);
        h2L[col] = lrelu(val);
    }
    __syncthreads();
    if (tid < 10) {
        float a = ldv(b2, tid, f32);
        for (int c = 0; c < 512; ++c) a += h2L[c] * ldv(W2, c * 10 + tid, f32);
        lgL[tid] = a;
    }
    __syncthreads();
    if (tid == 0) {
        float mx = lgL[0];
        for (int j = 1; j < 10; ++j) mx = fmaxf(mx, lgL[j]);
        float sum = 0.f, ex[10];
        for (int j = 0; j < 10; ++j) { ex[j] = expf(lgL[j] - mx); sum += ex[j]; }
        for (int j = 0; j < 10; ++j) {
            float p = ex[j] / sum;
            ypred[b * 10 + j] = p;
            stv(dout, b * 10 + j, p, f32);
        }
    }
}

// ---- losses: MMD on intra/inter attention + CE on softmaxed preds ----------
__global__ __launch_bounds__(256) void k_loss(
    const float* __restrict__ sa, const float* __restrict__ ta,
    const float* __restrict__ sb, const float* __restrict__ tb,
    const float* __restrict__ ypred, const int* __restrict__ sy,
    const int* __restrict__ flagp, void* __restrict__ dout)
{
    __shared__ float sA[8], sB[8];
    int f32 = *flagp;
    int tid = threadIdx.x;
    if (tid < 8) { sA[tid] = 0.f; sB[tid] = 0.f; }
    __syncthreads();
    if (tid < 128) {
        int f = tid >> 4, s = tid & 15;
        float d = 0.f;
        for (int b = 0; b < 16; ++b) d += sa[f * 256 + b * 16 + s] - ta[f * 256 + b * 16 + s];
        d *= (1.f / 16.f);
        atomicAdd(&sA[f], d * d);
    }
    for (int e = tid; e < 1024; e += 256) {
        int i = e >> 7, f = (e >> 4) & 7, s = e & 15;
        float d = 0.f;
        int base = ((i * 8 + f) * 16) * 16 + s;
        for (int b = 0; b < 16; ++b) d += sb[base + b * 16] - tb[base + b * 16];
        d *= (1.f / 16.f);
        atomicAdd(&sB[i], d * d);
    }
    __syncthreads();
    if (tid == 0) {
        float la = 0.f, lb = 0.f;
        for (int f = 0; f < 8; ++f) la += sqrtf(sA[f]);
        for (int i = 0; i < 8; ++i) lb += sqrtf(sB[i]);
        la *= 0.1f / 8.f;
        lb *= 0.1f / 8.f;
        float ce = 0.f;
        for (int b = 0; b < 16; ++b) {
            const float* y = ypred + b * 10;
            float mx = y[0];
            for (int j = 1; j < 10; ++j) mx = fmaxf(mx, y[j]);
            float sum = 0.f;
            for (int j = 0; j < 10; ++j) sum += expf(y[j] - mx);
            float lse = mx + logf(sum);
            ce += lse - y[sy[b]];
        }
        ce *= (1.f / 16.f);
        stv(dout, 160, ce + la + lb, f32);
    }
}

extern "C" void kernel_launch(void* const* d_in, const int* in_sizes, int n_in,
                              void* d_out, int out_size, void* d_ws, size_t ws_size,
                              hipStream_t stream) {
    (void)in_sizes; (void)n_in; (void)out_size; (void)ws_size;
    const void* src_x = d_in[0];
    const int*  src_y = (const int*)d_in[1];
    const void* tgt_x = d_in[2];
    const void *cw1 = d_in[3], *bn1g = d_in[4], *bn1b = d_in[5], *bn1m = d_in[6], *bn1v = d_in[7];
    const void *cw2 = d_in[8], *bn2g = d_in[9], *bn2b = d_in[10], *bn2m = d_in[11], *bn2v = d_in[12];
    const void *cw3 = d_in[13], *bn3g = d_in[14], *bn3b = d_in[15], *bn3m = d_in[16], *bn3v = d_in[17];
    const void *Wq = d_in[18], *bq = d_in[19], *Wk = d_in[20], *bk = d_in[21], *Wv = d_in[22], *bv = d_in[23];
    const void *bc1g = d_in[24], *bc1b = d_in[25], *bc1m = d_in[26], *bc1v = d_in[27];
    const void *W1 = d_in[28], *b1 = d_in[29];
    const void *bc2g = d_in[30], *bc2b = d_in[31], *bc2m = d_in[32], *bc2v = d_in[33];
    const void *W2 = d_in[34], *b2 = d_in[35];

    int* flag = (int*)d_ws;
    float* ws = (float*)d_ws + 16;
    size_t o = 0;
    float* rep    = ws + o; o += (size_t)8 * 256 * 128;
    float* Zn     = ws + o; o += (size_t)8 * 16 * 128;
    float* rninv  = ws + o; o += 2048;
    float* ia_s   = ws + o; o += 2048;
    float* ia_t   = ws + o; o += 2048;
    float* ib_s   = ws + o; o += 16384;
    float* ib_t   = ws + o; o += 16384;
    float* featbn = ws + o; o += (size_t)16 * 2048;
    float* ypred  = ws + o; o += 160;   // ~1.4 MB total

    // dtype probe on src_x (524288 u16 views if bf16, or 262144 f32 -> scan as 524288 u16)
    k_probe<<<1, 256, 0, stream>>>((const u16*)src_x, 524288, flag);

    for (int pass = 0; pass < 2; ++pass) {
        const void* x = pass ? tgt_x : src_x;
        float* ia = pass ? ia_t : ia_s;
        float* ib = pass ? ib_t : ib_s;
        k_cnn<<<2048, 256, 0, stream>>>(x,
            cw1, bn1g, bn1b, bn1m, bn1v,
            cw2, bn2g, bn2b, bn2m, bn2v,
            cw3, bn3g, bn3b, bn3m, bn3v, flag, rep);
        k_attn1<<<128, 128, 0, stream>>>(rep, Wq, bq, Wk, bk, Wv, bv, flag, Zn, rninv, ia);
        k_attn2<<<16, 256, 0, stream>>>(rep, Zn, rninv, ib, bc1g, bc1b, bc1m, bc1v,
                                        flag, featbn, pass == 0 ? 1 : 0);
    }
    k_head<<<16, 256, 0, stream>>>(featbn, W1, b1, bc2g, bc2b, bc2m, bc2v, W2, b2,
                                   flag, ypred, d_out);
    k_loss<<<1, 256, 0, stream>>>(ia_s, ia_t, ib_s, ib_t, ypred, src_y, flag, d_out);
}

// Round 4
// 1674.023 us; speedup vs baseline: 1.6780x; 1.6780x over previous
//
#include <hip/hip_runtime.h>

__device__ __forceinline__ float lrelu(float x) { return x >= 0.f ? x : 0.01f * x; }
__device__ __forceinline__ float eluf(float x)  { return x > 0.f ? x : expm1f(x); }

// sparsemax over 16 elements (Martins & Astudillo), exact ksup-count semantics
__device__ void sparsemax16(const float* z, float* out) {
    float zs[16];
    for (int i = 0; i < 16; ++i) zs[i] = z[i];
    for (int i = 1; i < 16; ++i) {
        float key = zs[i]; int j = i - 1;
        while (j >= 0 && zs[j] < key) { zs[j + 1] = zs[j]; --j; }
        zs[j + 1] = key;
    }
    float cum[16];
    cum[0] = zs[0];
    for (int i = 1; i < 16; ++i) cum[i] = cum[i - 1] + zs[i];
    int ksup = 0;
    for (int k = 1; k <= 16; ++k)
        if (1.0f + (float)k * zs[k - 1] > cum[k - 1]) ksup++;
    if (ksup < 1) ksup = 1;
    float tau = (cum[ksup - 1] - 1.0f) / (float)ksup;
    for (int i = 0; i < 16; ++i) out[i] = fmaxf(z[i] - tau, 0.0f);
}

__device__ __forceinline__ void load_w8(const float* p, size_t i8, float* wr) {
    const float4* q = reinterpret_cast<const float4*>(p + i8 * 8);
    float4 a = q[0], b = q[1];
    wr[0] = a.x; wr[1] = a.y; wr[2] = a.z; wr[3] = a.w;
    wr[4] = b.x; wr[5] = b.y; wr[6] = b.z; wr[7] = b.w;
}

// ===== fused CNN: conv1+bn+relu+pool -> conv2 -> conv3 -> mean  rep[8,256,128]
// LDS: s1[32][137] (4384) + s2[64][74] (4736) + scratch(896: xin 264 / partial 128x7)
//   = 10016 floats = 40064 B -> 4 blocks/CU
__global__ __launch_bounds__(256) void k_cnn(
    const float* __restrict__ x,
    const float* __restrict__ w1, const float* __restrict__ g1, const float* __restrict__ b1,
    const float* __restrict__ m1, const float* __restrict__ v1,
    const float* __restrict__ w2, const float* __restrict__ g2, const float* __restrict__ b2,
    const float* __restrict__ m2, const float* __restrict__ v2,
    const float* __restrict__ w3, const float* __restrict__ g3, const float* __restrict__ b3,
    const float* __restrict__ m3, const float* __restrict__ v3,
    float* __restrict__ rep)
{
    __shared__ float smem[10016];
    float* s1 = smem;                 // [32][137]
    float* s2 = smem + 4384;          // [64][74]
    float* scratch = smem + 9120;     // xin[264] then partial[128][7]

    int tid = threadIdx.x, blk = blockIdx.x;
    int f = blk >> 8, n = blk & 255, bb = n >> 4, ss = n & 15;

    // zero pads + stage input
    for (int i = tid; i < 9120; i += 256) smem[i] = 0.f;
    for (int i = tid; i < 264; i += 256) scratch[i] = 0.f;
    __syncthreads();
    const float* xr = x + (((size_t)bb * 8 + f) * 16 + ss) * 256;
    for (int i = tid; i < 256; i += 256) scratch[i + 4] = xr[i];
    __syncthreads();

    // ---- conv1 (1->32, 256 -> conv 257 -> pool 129) ----
    // tiles: 8 cc(4 co) x 26 jc(5 pooled j) = 208
    if (tid < 208) {
        int cc = tid & 7, jc = tid >> 3;
        int co0 = cc * 4, j0 = jc * 5;
        float wr[4][8];
        for (int c = 0; c < 4; ++c) load_w8(w1, (size_t)f * 32 + co0 + c, wr[c]);
        int px[10];
        for (int i = 0; i < 10; ++i) {
            int p = 2 * j0 - 1 + i;
            px[i] = p < 0 ? 0 : (p > 256 ? 256 : p);
        }
        float acc[4][10];
        for (int c = 0; c < 4; ++c) for (int i = 0; i < 10; ++i) acc[c][i] = 0.f;
        for (int k = 0; k < 8; ++k) {
            float xv[10];
            for (int i = 0; i < 10; ++i) xv[i] = scratch[px[i] + k];
            for (int c = 0; c < 4; ++c)
                for (int i = 0; i < 10; ++i) acc[c][i] += wr[c][k] * xv[i];
        }
        for (int c = 0; c < 4; ++c) {
            int co = co0 + c;
            float sc = g1[f * 32 + co] * rsqrtf(v1[f * 32 + co] + 1e-5f);
            float sh = b1[f * 32 + co] - m1[f * 32 + co] * sc;
            for (int jj = 0; jj < 5; ++jj) {
                int j = j0 + jj;
                if (j < 129) {
                    float a0 = fmaxf(acc[c][2 * jj] * sc + sh, 0.f);
                    float a1 = fmaxf(acc[c][2 * jj + 1] * sc + sh, 0.f);
                    s1[co * 137 + 4 + j] = fmaxf(a0, a1);
                }
            }
        }
    }
    __syncthreads();

    // ---- conv2 (32->64, 129 -> conv 130 -> pool 66) ----
    // tiles: 16 cc x 14 jc(5) = 224
    if (tid < 224) {
        int cc = tid & 15, jc = tid >> 4;
        int co0 = cc * 4, j0 = jc * 5;
        int px[10];
        for (int i = 0; i < 10; ++i) {
            int p = 2 * j0 - 1 + i;
            px[i] = p < 0 ? 0 : (p > 129 ? 129 : p);
        }
        float acc[4][10];
        for (int c = 0; c < 4; ++c) for (int i = 0; i < 10; ++i) acc[c][i] = 0.f;
        for (int ci = 0; ci < 32; ++ci) {
            float wr[4][8];
            for (int c = 0; c < 4; ++c)
                load_w8(w2, ((size_t)f * 64 + co0 + c) * 32 + ci, wr[c]);
            const float* row = s1 + ci * 137;
            for (int k = 0; k < 8; ++k) {
                float xv[10];
                for (int i = 0; i < 10; ++i) xv[i] = row[px[i] + k];
                for (int c = 0; c < 4; ++c)
                    for (int i = 0; i < 10; ++i) acc[c][i] += wr[c][k] * xv[i];
            }
        }
        for (int c = 0; c < 4; ++c) {
            int co = co0 + c;
            float sc = g2[f * 64 + co] * rsqrtf(v2[f * 64 + co] + 1e-5f);
            float sh = b2[f * 64 + co] - m2[f * 64 + co] * sc;
            for (int jj = 0; jj < 5; ++jj) {
                int j = j0 + jj;
                if (j < 66) {
                    float a0 = fmaxf(acc[c][2 * jj] * sc + sh, 0.f);
                    float a1 = fmaxf(acc[c][2 * jj + 1] * sc + sh, 0.f);
                    s2[co * 74 + 4 + j] = fmaxf(a0, a1);
                }
            }
        }
    }
    __syncthreads();

    // ---- conv3 (64->128, 66 -> conv 67 -> pool 34 -> mean) ----
    // tiles: 32 cc x 7 jc(5) = 224;  partial[128][7] in scratch
    if (tid < 224) {
        int cc = tid & 31, jc = tid >> 5;
        int co0 = cc * 4, j0 = jc * 5;
        int px[10];
        for (int i = 0; i < 10; ++i) {
            int p = 2 * j0 - 1 + i;
            px[i] = p < 0 ? 0 : (p > 66 ? 66 : p);
        }
        float acc[4][10];
        for (int c = 0; c < 4; ++c) for (int i = 0; i < 10; ++i) acc[c][i] = 0.f;
        for (int ci = 0; ci < 64; ++ci) {
            float wr[4][8];
            for (int c = 0; c < 4; ++c)
                load_w8(w3, ((size_t)f * 128 + co0 + c) * 64 + ci, wr[c]);
            const float* row = s2 + ci * 74;
            for (int k = 0; k < 8; ++k) {
                float xv[10];
                for (int i = 0; i < 10; ++i) xv[i] = row[px[i] + k];
                for (int c = 0; c < 4; ++c)
                    for (int i = 0; i < 10; ++i) acc[c][i] += wr[c][k] * xv[i];
            }
        }
        for (int c = 0; c < 4; ++c) {
            int co = co0 + c;
            float sc = g3[f * 128 + co] * rsqrtf(v3[f * 128 + co] + 1e-5f);
            float sh = b3[f * 128 + co] - m3[f * 128 + co] * sc;
            float sum = 0.f;
            for (int jj = 0; jj < 5; ++jj) {
                int j = j0 + jj;
                if (j < 34) {
                    float a0 = fmaxf(acc[c][2 * jj] * sc + sh, 0.f);
                    float a1 = fmaxf(acc[c][2 * jj + 1] * sc + sh, 0.f);
                    sum += fmaxf(a0, a1);
                }
            }
            scratch[co * 7 + jc] = sum;
        }
    }
    __syncthreads();
    if (tid < 128) {
        float s = 0.f;
        for (int jc = 0; jc < 7; ++jc) s += scratch[tid * 7 + jc];
        rep[(((size_t)f * 256) + n) * 128 + tid] = s * (1.0f / 34.0f);
    }
}

// ---- QKV + scores + intra sparsemax + Z(normalized) + rep inv-norms --------
__global__ __launch_bounds__(128) void k_attn1(
    const float* __restrict__ rep,
    const float* __restrict__ Wq, const float* __restrict__ bq,
    const float* __restrict__ Wk, const float* __restrict__ bk,
    const float* __restrict__ Wv, const float* __restrict__ bv,
    float* __restrict__ Zn, float* __restrict__ rninv, float* __restrict__ iaw)
{
    __shared__ float repL[2048], QL[2048], VL[2048];
    __shared__ float KmL[128], red[128], scoresL[16], awL[16];
    int tid = threadIdx.x;
    int f = blockIdx.x >> 4, b = blockIdx.x & 15;
    const float* rb = rep + ((size_t)f * 256 + b * 16) * 128;
    for (int i = tid; i < 2048; i += 128) repL[i] = rb[i];
    __syncthreads();

    int h2 = tid;
    float km = 0.f;
    float bqv = bq[h2], bkv = bk[h2], bvv = bv[h2];
    for (int s0 = 0; s0 < 16; s0 += 8) {
        float aq[8], ak[8], av[8];
        for (int t = 0; t < 8; ++t) { aq[t] = bqv; ak[t] = bkv; av[t] = bvv; }
        for (int h = 0; h < 128; ++h) {
            float wq = Wq[h * 128 + h2];
            float wk = Wk[h * 128 + h2];
            float wv = Wv[h * 128 + h2];
            for (int t = 0; t < 8; ++t) {
                float r = repL[(s0 + t) * 128 + h];
                aq[t] += r * wq; ak[t] += r * wk; av[t] += r * wv;
            }
        }
        for (int t = 0; t < 8; ++t) {
            QL[(s0 + t) * 128 + h2] = eluf(aq[t]);
            VL[(s0 + t) * 128 + h2] = lrelu(av[t]);
            km += lrelu(ak[t]);
        }
    }
    KmL[h2] = km * (1.f / 16.f);
    __syncthreads();

    if (tid < 16) {
        float a = 0.f;
        for (int h = 0; h < 128; ++h) a += QL[tid * 128 + h] * KmL[h];
        scoresL[tid] = a * 0.08838834764831845f;   // 1/sqrt(128)
        float r2 = 0.f;
        for (int h = 0; h < 128; ++h) { float r = repL[tid * 128 + h]; r2 += r * r; }
        rninv[f * 256 + b * 16 + tid] = 1.f / fmaxf(sqrtf(r2), 1e-12f);
    }
    __syncthreads();
    if (tid == 0) sparsemax16(scoresL, awL);
    __syncthreads();
    if (tid < 16) iaw[f * 256 + b * 16 + tid] = awL[tid];

    float z = 0.f;
    for (int s = 0; s < 16; ++s) z += awL[s] * VL[s * 128 + tid];
    red[tid] = z * z;
    __syncthreads();
    for (int st = 64; st > 0; st >>= 1) {
        if (tid < st) red[tid] += red[tid + st];
        __syncthreads();
    }
    float inv = 1.f / fmaxf(sqrtf(red[0]), 1e-12f);
    Zn[((size_t)f * 16 + b) * 128 + tid] = z * inv;
}

// ---- inter scores + sparsemax + U + Hc + BN(feat) --------------------------
__global__ __launch_bounds__(256) void k_attn2(
    const float* __restrict__ rep, const float* __restrict__ Zn,
    const float* __restrict__ rninv, float* __restrict__ ibw,
    const float* __restrict__ g, const float* __restrict__ bb,
    const float* __restrict__ mm, const float* __restrict__ vv,
    float* __restrict__ featbn, int write_feat)
{
    __shared__ float ZnL[1024], sc[1024], UL[1024], nrm[8];
    int tid = threadIdx.x, b = blockIdx.x;
    for (int i = tid; i < 1024; i += 256) {
        int ii = i >> 7, h = i & 127;
        ZnL[i] = Zn[((size_t)ii * 16 + b) * 128 + h];
    }
    if (tid < 8) nrm[tid] = 0.f;
    __syncthreads();

    for (int e = tid; e < 1024; e += 256) {
        int i = e >> 7, f = (e >> 4) & 7, s = e & 15;
        const float* rr = rep + ((size_t)f * 256 + b * 16 + s) * 128;
        float a = 0.f;
        for (int h = 0; h < 128; ++h) a += ZnL[i * 128 + h] * rr[h];
        sc[(i * 8 + f) * 16 + s] = a * rninv[f * 256 + b * 16 + s];
    }
    __syncthreads();
    if (tid < 64) {
        int i = tid >> 3, f = tid & 7;
        float aw[16];
        sparsemax16(&sc[(i * 8 + f) * 16], aw);
        for (int s = 0; s < 16; ++s) {
            sc[(i * 8 + f) * 16 + s] = aw[s];
            ibw[(((size_t)i * 8 + f) * 16 + b) * 16 + s] = aw[s];
        }
    }
    __syncthreads();
    for (int e = tid; e < 1024; e += 256) {
        int i = e >> 7, h = e & 127;
        float u = 0.f;
        for (int f = 0; f < 8; ++f) {
            const float* rr = rep + ((size_t)f * 256 + b * 16) * 128 + h;
            const float* aa = &sc[(i * 8 + f) * 16];
            for (int s = 0; s < 16; ++s) u += aa[s] * rr[s * 128];
        }
        UL[e] = u * 0.125f;
    }
    __syncthreads();
    if (write_feat) {
        for (int e = tid; e < 1024; e += 256) {
            int f = e >> 7;
            float zz = ZnL[e], uu = UL[e];
            atomicAdd(&nrm[f], zz * zz + uu * uu);
        }
        __syncthreads();
        for (int e = tid; e < 2048; e += 256) {
            int f = e >> 8, d = e & 255;
            float inv = 1.f / fmaxf(sqrtf(nrm[f]), 1e-12f);
            float val = (d < 128 ? ZnL[f * 128 + d] : UL[f * 128 + d - 128]) * inv;
            float scv = g[e] * rsqrtf(vv[e] + 1e-5f);
            featbn[b * 2048 + e] = (val - mm[e]) * scv + bb[e];
        }
    }
}

// ---- dense head: bn(feat)@W1+b1, bn2, leaky, @W2+b2, softmax ---------------
__global__ __launch_bounds__(256) void k_head(
    const float* __restrict__ featbn,
    const float* __restrict__ W1, const float* __restrict__ b1,
    const float* __restrict__ g2, const float* __restrict__ bb2,
    const float* __restrict__ mm2, const float* __restrict__ vv2,
    const float* __restrict__ W2, const float* __restrict__ b2,
    float* __restrict__ ypred, float* __restrict__ dout)
{
    __shared__ float featL[2048], h2L[512], lgL[10];
    int tid = threadIdx.x, b = blockIdx.x;
    for (int i = tid; i < 2048; i += 256) featL[i] = featbn[b * 2048 + i];
    __syncthreads();
    for (int col = tid; col < 512; col += 256) {
        float a = b1[col];
        for (int c = 0; c < 2048; ++c) a += featL[c] * W1[(size_t)c * 512 + col];
        float scv = g2[col] * rsqrtf(vv2[col] + 1e-5f);
        float val = (a - mm2[col]) * scv + bb2[col];
        h2L[col] = lrelu(val);
    }
    __syncthreads();
    if (tid < 10) {
        float a = b2[tid];
        for (int c = 0; c < 512; ++c) a += h2L[c] * W2[c * 10 + tid];
        lgL[tid] = a;
    }
    __syncthreads();
    if (tid == 0) {
        float mx = lgL[0];
        for (int j = 1; j < 10; ++j) mx = fmaxf(mx, lgL[j]);
        float sum = 0.f, ex[10];
        for (int j = 0; j < 10; ++j) { ex[j] = expf(lgL[j] - mx); sum += ex[j]; }
        for (int j = 0; j < 10; ++j) {
            float p = ex[j] / sum;
            ypred[b * 10 + j] = p;
            dout[b * 10 + j] = p;
        }
    }
}

// ---- losses: MMD on intra/inter attention + CE on softmaxed preds ----------
__global__ __launch_bounds__(256) void k_loss(
    const float* __restrict__ sa, const float* __restrict__ ta,
    const float* __restrict__ sb, const float* __restrict__ tb,
    const float* __restrict__ ypred, const int* __restrict__ sy,
    float* __restrict__ dout)
{
    __shared__ float sA[8], sB[8];
    int tid = threadIdx.x;
    if (tid < 8) { sA[tid] = 0.f; sB[tid] = 0.f; }
    __syncthreads();
    if (tid < 128) {
        int f = tid >> 4, s = tid & 15;
        float d = 0.f;
        for (int b = 0; b < 16; ++b) d += sa[f * 256 + b * 16 + s] - ta[f * 256 + b * 16 + s];
        d *= (1.f / 16.f);
        atomicAdd(&sA[f], d * d);
    }
    for (int e = tid; e < 1024; e += 256) {
        int i = e >> 7, f = (e >> 4) & 7, s = e & 15;
        float d = 0.f;
        int base = ((i * 8 + f) * 16) * 16 + s;
        for (int b = 0; b < 16; ++b) d += sb[base + b * 16] - tb[base + b * 16];
        d *= (1.f / 16.f);
        atomicAdd(&sB[i], d * d);
    }
    __syncthreads();
    if (tid == 0) {
        float la = 0.f, lb = 0.f;
        for (int f = 0; f < 8; ++f) la += sqrtf(sA[f]);
        for (int i = 0; i < 8; ++i) lb += sqrtf(sB[i]);
        la *= 0.1f / 8.f;
        lb *= 0.1f / 8.f;
        float ce = 0.f;
        for (int b = 0; b < 16; ++b) {
            const float* y = ypred + b * 10;
            float mx = y[0];
            for (int j = 1; j < 10; ++j) mx = fmaxf(mx, y[j]);
            float sum = 0.f;
            for (int j = 0; j < 10; ++j) sum += expf(y[j] - mx);
            float lse = mx + logf(sum);
            ce += lse - y[sy[b]];
        }
        ce *= (1.f / 16.f);
        dout[160] = ce + la + lb;
    }
}

extern "C" void kernel_launch(void* const* d_in, const int* in_sizes, int n_in,
                              void* d_out, int out_size, void* d_ws, size_t ws_size,
                              hipStream_t stream) {
    (void)in_sizes; (void)n_in; (void)out_size; (void)ws_size;
    const float* src_x = (const float*)d_in[0];
    const int*   src_y = (const int*)d_in[1];
    const float* tgt_x = (const float*)d_in[2];
    const float *cw1 = (const float*)d_in[3], *bn1g = (const float*)d_in[4],
                *bn1b = (const float*)d_in[5], *bn1m = (const float*)d_in[6],
                *bn1v = (const float*)d_in[7];
    const float *cw2 = (const float*)d_in[8], *bn2g = (const float*)d_in[9],
                *bn2b = (const float*)d_in[10], *bn2m = (const float*)d_in[11],
                *bn2v = (const float*)d_in[12];
    const float *cw3 = (const float*)d_in[13], *bn3g = (const float*)d_in[14],
                *bn3b = (const float*)d_in[15], *bn3m = (const float*)d_in[16],
                *bn3v = (const float*)d_in[17];
    const float *Wq = (const float*)d_in[18], *bq = (const float*)d_in[19],
                *Wk = (const float*)d_in[20], *bk = (const float*)d_in[21],
                *Wv = (const float*)d_in[22], *bv = (const float*)d_in[23];
    const float *bc1g = (const float*)d_in[24], *bc1b = (const float*)d_in[25],
                *bc1m = (const float*)d_in[26], *bc1v = (const float*)d_in[27];
    const float *W1 = (const float*)d_in[28], *b1 = (const float*)d_in[29];
    const float *bc2g = (const float*)d_in[30], *bc2b = (const float*)d_in[31],
                *bc2m = (const float*)d_in[32], *bc2v = (const float*)d_in[33];
    const float *W2 = (const float*)d_in[34], *b2 = (const float*)d_in[35];

    float* ws = (float*)d_ws;
    size_t o = 0;
    float* rep    = ws + o; o += (size_t)8 * 256 * 128;
    float* Zn     = ws + o; o += (size_t)8 * 16 * 128;
    float* rninv  = ws + o; o += 2048;
    float* ia_s   = ws + o; o += 2048;
    float* ia_t   = ws + o; o += 2048;
    float* ib_s   = ws + o; o += 16384;
    float* ib_t   = ws + o; o += 16384;
    float* featbn = ws + o; o += (size_t)16 * 2048;
    float* ypred  = ws + o; o += 160;

    for (int pass = 0; pass < 2; ++pass) {
        const float* x = pass ? tgt_x : src_x;
        float* ia = pass ? ia_t : ia_s;
        float* ib = pass ? ib_t : ib_s;
        k_cnn<<<2048, 256, 0, stream>>>(x,
            cw1, bn1g, bn1b, bn1m, bn1v,
            cw2, bn2g, bn2b, bn2m, bn2v,
            cw3, bn3g, bn3b, bn3m, bn3v, rep);
        k_attn1<<<128, 128, 0, stream>>>(rep, Wq, bq, Wk, bk, Wv, bv, Zn, rninv, ia);
        k_attn2<<<16, 256, 0, stream>>>(rep, Zn, rninv, ib, bc1g, bc1b, bc1m, bc1v,
                                        featbn, pass == 0 ? 1 : 0);
    }
    k_head<<<16, 256, 0, stream>>>(featbn, W1, b1, bc2g, bc2b, bc2m, bc2v, W2, b2,
                                   ypred, (float*)d_out);
    k_loss<<<1, 256, 0, stream>>>(ia_s, ia_t, ib_s, ib_t, ypred, src_y, (float*)d_out);
}

// Round 5
// 445.102 us; speedup vs baseline: 6.3108x; 3.7610x over previous
//
#include <hip/hip_runtime.h>

typedef unsigned short u16;
typedef unsigned int u32;
typedef __attribute__((ext_vector_type(8))) short bfrag;   // 8 bf16
typedef __attribute__((ext_vector_type(4))) float ffrag;   // 4 fp32 acc

__device__ __forceinline__ float lrelu(float x) { return x >= 0.f ? x : 0.01f * x; }
__device__ __forceinline__ float eluf(float x)  { return x > 0.f ? x : expm1f(x); }
__device__ __forceinline__ u16 f2bf(float f) {
    u32 x = __float_as_uint(f);
    return (u16)((x + 0x7fffu + ((x >> 16) & 1u)) >> 16);
}
__device__ __forceinline__ float bf2f(u16 u) {
    return __uint_as_float(((u32)u) << 16);
}

// sparsemax over 16 elements (Martins & Astudillo), exact ksup-count semantics
__device__ void sparsemax16(const float* z, float* out) {
    float zs[16];
    for (int i = 0; i < 16; ++i) zs[i] = z[i];
    for (int i = 1; i < 16; ++i) {
        float key = zs[i]; int j = i - 1;
        while (j >= 0 && zs[j] < key) { zs[j + 1] = zs[j]; --j; }
        zs[j + 1] = key;
    }
    float cum[16];
    cum[0] = zs[0];
    for (int i = 1; i < 16; ++i) cum[i] = cum[i - 1] + zs[i];
    int ksup = 0;
    for (int k = 1; k <= 16; ++k)
        if (1.0f + (float)k * zs[k - 1] > cum[k - 1]) ksup++;
    if (ksup < 1) ksup = 1;
    float tau = (cum[ksup - 1] - 1.0f) / (float)ksup;
    for (int i = 0; i < 16; ++i) out[i] = fmaxf(z[i] - tau, 0.0f);
}

// ---- weight pre-pack into B-fragment order (bf16) --------------------------
// Wpk2[f][nt:4][kc:8][lane:64][j:8]  = w2[f, co=nt*16+(L&15), ci=(L>>4)*8+j, kk=kc]
// Wpk3[f][nt:8][kc:16][lane:64][j:8] = w3[f, co=nt*16+(L&15), ci=32*(kc&1)+(L>>4)*8+j, kk=kc>>1]
__global__ __launch_bounds__(256) void k_wprep(
    const float* __restrict__ w2, const float* __restrict__ w3,
    u16* __restrict__ wpk2, u16* __restrict__ wpk3)
{
    int i = blockIdx.x * 256 + threadIdx.x;
    if (i < 131072) {
        int j = i & 7, L = (i >> 3) & 63, kc = (i >> 9) & 7, nt = (i >> 12) & 3, f = i >> 14;
        int co = nt * 16 + (L & 15);
        int ci = ((L >> 4) << 3) + j;
        wpk2[i] = f2bf(w2[(((size_t)f * 64 + co) * 32 + ci) * 8 + kc]);
    } else if (i < 131072 + 524288) {
        int i2 = i - 131072;
        int j = i2 & 7, L = (i2 >> 3) & 63, kc = (i2 >> 9) & 15, nt = (i2 >> 13) & 7, f = i2 >> 16;
        int co = nt * 16 + (L & 15);
        int ci = ((kc & 1) << 5) + ((L >> 4) << 3) + j;
        wpk3[i2] = f2bf(w3[(((size_t)f * 128 + co) * 64 + ci) * 8 + (kc >> 1)]);
    }
}

// ===== fused CNN (both passes): conv1 fp32 -> conv2/conv3 bf16 MFMA ==========
// LDS layout (u16 units):
//   regionA [0, 6336):   s1T rows 152 x stride 40  (then reused as s2T rows 88 x 72)
//   regionB [6336, ...): xin (264 f32) / c2raw 130x64 / c3raw 67x136
#define S1T_STRIDE 40
#define S2T_STRIDE 72
#define RB_OFF 6336
#define SMEM_U16 15448

__global__ __launch_bounds__(256) void k_cnn(
    const float* __restrict__ xs, const float* __restrict__ xt,
    const float* __restrict__ w1, const float* __restrict__ g1, const float* __restrict__ b1,
    const float* __restrict__ m1, const float* __restrict__ v1,
    const float* __restrict__ g2, const float* __restrict__ b2,
    const float* __restrict__ m2, const float* __restrict__ v2,
    const float* __restrict__ g3, const float* __restrict__ b3,
    const float* __restrict__ m3, const float* __restrict__ v3,
    const u16* __restrict__ wpk2, const u16* __restrict__ wpk3,
    float* __restrict__ rep)
{
    __shared__ __align__(16) u16 smem[SMEM_U16];
    float* xin = (float*)(smem + RB_OFF);      // 264 floats

    int tid = threadIdx.x, blk = blockIdx.x;
    int pass = blk >> 11, f = (blk >> 8) & 7, n = blk & 255;
    int bb = n >> 4, ss = n & 15;
    int lane = tid & 63, w = tid >> 6;
    const float* x = pass ? xt : xs;
    float* rep_p = rep + (size_t)pass * 262144;

    // ---- phase 0: zero s1T region + xin pads, stage input ----
    {
        u32* z = (u32*)smem;
        for (int i = tid; i < 3168; i += 256) z[i] = 0;   // s1T region (6336 u16)
        for (int i = tid; i < 264; i += 256) xin[i] = 0.f;
    }
    __syncthreads();
    {
        const float* xr = x + (((size_t)bb * 8 + f) * 16 + ss) * 256;
        for (int i = tid; i < 256; i += 256) xin[i + 4] = xr[i];
    }
    __syncthreads();

    // ---- phase 1: conv1 fp32 (1->32, 256 -> conv 257 -> pool 129) ----
    // writes s1T[(j+4)*40 + co] bf16, j in [0,128]
    if (tid < 208) {
        int cc = tid & 7, jc = tid >> 3;
        int co0 = cc * 4, j0 = jc * 5;
        float wr[4][8];
        for (int c = 0; c < 4; ++c) {
            const float4* q = reinterpret_cast<const float4*>(w1 + ((size_t)f * 32 + co0 + c) * 8);
            float4 a = q[0], bq = q[1];
            wr[c][0] = a.x; wr[c][1] = a.y; wr[c][2] = a.z; wr[c][3] = a.w;
            wr[c][4] = bq.x; wr[c][5] = bq.y; wr[c][6] = bq.z; wr[c][7] = bq.w;
        }
        int px[10];
        for (int i = 0; i < 10; ++i) {
            int p = 2 * j0 - 1 + i;
            px[i] = p < 0 ? 0 : (p > 256 ? 256 : p);
        }
        float acc[4][10];
        for (int c = 0; c < 4; ++c) for (int i = 0; i < 10; ++i) acc[c][i] = 0.f;
        for (int k = 0; k < 8; ++k) {
            float xv[10];
            for (int i = 0; i < 10; ++i) xv[i] = xin[px[i] + k];
            for (int c = 0; c < 4; ++c)
                for (int i = 0; i < 10; ++i) acc[c][i] += wr[c][k] * xv[i];
        }
        for (int c = 0; c < 4; ++c) {
            int co = co0 + c;
            float sc = g1[f * 32 + co] * rsqrtf(v1[f * 32 + co] + 1e-5f);
            float sh = b1[f * 32 + co] - m1[f * 32 + co] * sc;
            for (int jj = 0; jj < 5; ++jj) {
                int j = j0 + jj;
                if (j < 129) {
                    float a0 = fmaxf(acc[c][2 * jj] * sc + sh, 0.f);
                    float a1 = fmaxf(acc[c][2 * jj + 1] * sc + sh, 0.f);
                    smem[(j + 4) * S1T_STRIDE + co] = f2bf(fmaxf(a0, a1));
                }
            }
        }
    }
    __syncthreads();

    // ---- phase 2: conv2 MFMA (M=130 pos, N=64 co, K=256) ----
    // A[p][k'=kk*32+ci] = s1T[p+kk][ci]; chunk kc: kk=kc, ci=(L>>4)*8+j
    {
        int nt = w;                                  // 4 n-tiles, 1 per wave
        bfrag B2[8];
        const bfrag* gB = reinterpret_cast<const bfrag*>(wpk2);
        for (int kc = 0; kc < 8; ++kc)
            B2[kc] = gB[(((size_t)f * 4 + nt) * 8 + kc) * 64 + lane];
        int co = nt * 16 + (lane & 15);
        float sc = g2[f * 64 + co] * rsqrtf(v2[f * 64 + co] + 1e-5f);
        float sh = b2[f * 64 + co] - m2[f * 64 + co] * sc;
        int arow = lane & 15, ci0 = (lane >> 4) << 3;
        for (int mt = 0; mt < 9; ++mt) {
            ffrag C = {0.f, 0.f, 0.f, 0.f};
            int rb = mt * 16 + arow;
            for (int kc = 0; kc < 8; ++kc) {
                bfrag A = *reinterpret_cast<const bfrag*>(&smem[(rb + kc) * S1T_STRIDE + ci0]);
                C = __builtin_amdgcn_mfma_f32_16x16x32_bf16(A, B2[kc], C, 0, 0, 0);
            }
            int p0 = mt * 16 + ((lane >> 4) << 2);
            for (int r = 0; r < 4; ++r) {
                int p = p0 + r;
                if (p < 130)
                    smem[RB_OFF + p * 64 + co] = f2bf(fmaxf(C[r] * sc + sh, 0.f));
            }
        }
    }
    __syncthreads();

    // ---- phase 3: zero s2T region (overlaps dead s1T) ----
    {
        u32* z = (u32*)smem;
        for (int i = tid; i < 3168; i += 256) z[i] = 0;
    }
    __syncthreads();

    // ---- phase 4: pool conv2 -> s2T[(j+4)*72 + ci], j in [0,65] ----
    for (int e = tid; e < 66 * 64; e += 256) {
        int j = e >> 6, ci = e & 63;
        u16 v0 = smem[RB_OFF + (2 * j) * 64 + ci];           // p=2j (<=130? j=65 -> 130 invalid)
        float vmax;
        if (j == 0) {
            vmax = bf2f(smem[RB_OFF + 0 * 64 + ci]);
        } else if (j == 65) {
            vmax = bf2f(smem[RB_OFF + 129 * 64 + ci]);
        } else {
            float a0 = bf2f(smem[RB_OFF + (2 * j - 1) * 64 + ci]);
            float a1 = bf2f(v0);
            vmax = fmaxf(a0, a1);
        }
        smem[(j + 4) * S2T_STRIDE + ci] = f2bf(vmax);
    }
    __syncthreads();

    // ---- phase 5: conv3 MFMA (M=67 pos, N=128 co, K=512) ----
    // A[p][k'=kk*64+ci] = s2T[p+kk][ci]; chunk kc: kk=kc>>1, ci=32*(kc&1)+(L>>4)*8+j
    for (int t = 0; t < 2; ++t) {
        int nt = w * 2 + t;                          // 8 n-tiles, 2 per wave
        bfrag B3[16];
        const bfrag* gB = reinterpret_cast<const bfrag*>(wpk3);
        for (int kc = 0; kc < 16; ++kc)
            B3[kc] = gB[(((size_t)f * 8 + nt) * 16 + kc) * 64 + lane];
        int co = nt * 16 + (lane & 15);
        float sc = g3[f * 128 + co] * rsqrtf(v3[f * 128 + co] + 1e-5f);
        float sh = b3[f * 128 + co] - m3[f * 128 + co] * sc;
        int arow = lane & 15, q8 = (lane >> 4) << 3;
        for (int mt = 0; mt < 5; ++mt) {
            ffrag C = {0.f, 0.f, 0.f, 0.f};
            int rb = mt * 16 + arow;
            for (int kc = 0; kc < 16; ++kc) {
                int row = rb + (kc >> 1);
                int ci0 = ((kc & 1) << 5) + q8;
                bfrag A = *reinterpret_cast<const bfrag*>(&smem[row * S2T_STRIDE + ci0]);
                C = __builtin_amdgcn_mfma_f32_16x16x32_bf16(A, B3[kc], C, 0, 0, 0);
            }
            int p0 = mt * 16 + ((lane >> 4) << 2);
            for (int r = 0; r < 4; ++r) {
                int p = p0 + r;
                if (p < 67)
                    smem[RB_OFF + p * 136 + co] = f2bf(fmaxf(C[r] * sc + sh, 0.f));
            }
        }
    }
    __syncthreads();

    // ---- phase 6: pool conv3 + mean -> rep ----
    if (tid < 128) {
        int co = tid;
        float sum = bf2f(smem[RB_OFF + 0 * 136 + co]);       // j=0: only p=0
        for (int j = 1; j < 34; ++j) {
            float a0 = bf2f(smem[RB_OFF + (2 * j - 1) * 136 + co]);
            float a1 = bf2f(smem[RB_OFF + (2 * j) * 136 + co]);
            sum += fmaxf(a0, a1);
        }
        rep_p[(((size_t)f * 256) + n) * 128 + co] = sum * (1.0f / 34.0f);
    }
}

// ---- QKV + scores + intra sparsemax + Z(normalized) + rep inv-norms --------
__global__ __launch_bounds__(128) void k_attn1(
    const float* __restrict__ rep,
    const float* __restrict__ Wq, const float* __restrict__ bq,
    const float* __restrict__ Wk, const float* __restrict__ bk,
    const float* __restrict__ Wv, const float* __restrict__ bv,
    float* __restrict__ Zn, float* __restrict__ rninv, float* __restrict__ iaw)
{
    __shared__ float repL[2048], QL[2048], VL[2048];
    __shared__ float KmL[128], red[128], scoresL[16], awL[16];
    int tid = threadIdx.x;
    int pass = blockIdx.x >> 7, f = (blockIdx.x >> 4) & 7, b = blockIdx.x & 15;
    const float* rep_p = rep + (size_t)pass * 262144;
    float* Zn_p = Zn + (size_t)pass * 16384;
    float* rninv_p = rninv + (size_t)pass * 2048;
    float* iaw_p = iaw + (size_t)pass * 2048;

    const float* rb = rep_p + ((size_t)f * 256 + b * 16) * 128;
    for (int i = tid; i < 2048; i += 128) repL[i] = rb[i];
    __syncthreads();

    int h2 = tid;
    float km = 0.f;
    float bqv = bq[h2], bkv = bk[h2], bvv = bv[h2];
    for (int s0 = 0; s0 < 16; s0 += 8) {
        float aq[8], ak[8], av[8];
        for (int t = 0; t < 8; ++t) { aq[t] = bqv; ak[t] = bkv; av[t] = bvv; }
        for (int h = 0; h < 128; ++h) {
            float wq = Wq[h * 128 + h2];
            float wk = Wk[h * 128 + h2];
            float wv = Wv[h * 128 + h2];
            for (int t = 0; t < 8; ++t) {
                float r = repL[(s0 + t) * 128 + h];
                aq[t] += r * wq; ak[t] += r * wk; av[t] += r * wv;
            }
        }
        for (int t = 0; t < 8; ++t) {
            QL[(s0 + t) * 128 + h2] = eluf(aq[t]);
            VL[(s0 + t) * 128 + h2] = lrelu(av[t]);
            km += lrelu(ak[t]);
        }
    }
    KmL[h2] = km * (1.f / 16.f);
    __syncthreads();

    if (tid < 16) {
        float a = 0.f;
        for (int h = 0; h < 128; ++h) a += QL[tid * 128 + h] * KmL[h];
        scoresL[tid] = a * 0.08838834764831845f;   // 1/sqrt(128)
        float r2 = 0.f;
        for (int h = 0; h < 128; ++h) { float r = repL[tid * 128 + h]; r2 += r * r; }
        rninv_p[f * 256 + b * 16 + tid] = 1.f / fmaxf(sqrtf(r2), 1e-12f);
    }
    __syncthreads();
    if (tid == 0) sparsemax16(scoresL, awL);
    __syncthreads();
    if (tid < 16) iaw_p[f * 256 + b * 16 + tid] = awL[tid];

    float z = 0.f;
    for (int s = 0; s < 16; ++s) z += awL[s] * VL[s * 128 + tid];
    red[tid] = z * z;
    __syncthreads();
    for (int st = 64; st > 0; st >>= 1) {
        if (tid < st) red[tid] += red[tid + st];
        __syncthreads();
    }
    float inv = 1.f / fmaxf(sqrtf(red[0]), 1e-12f);
    Zn_p[((size_t)f * 16 + b) * 128 + tid] = z * inv;
}

// ---- inter scores + sparsemax + U + Hc + BN(feat) --------------------------
__global__ __launch_bounds__(256) void k_attn2(
    const float* __restrict__ rep, const float* __restrict__ Zn,
    const float* __restrict__ rninv, float* __restrict__ ibw,
    const float* __restrict__ g, const float* __restrict__ bb,
    const float* __restrict__ mm, const float* __restrict__ vv,
    float* __restrict__ featbn)
{
    __shared__ float ZnL[1024], sc[1024], UL[1024], nrm[8];
    int tid = threadIdx.x;
    int pass = blockIdx.x >> 4, b = blockIdx.x & 15;
    const float* rep_p = rep + (size_t)pass * 262144;
    const float* Zn_p = Zn + (size_t)pass * 16384;
    const float* rninv_p = rninv + (size_t)pass * 2048;
    float* ibw_p = ibw + (size_t)pass * 16384;

    for (int i = tid; i < 1024; i += 256) {
        int ii = i >> 7, h = i & 127;
        ZnL[i] = Zn_p[((size_t)ii * 16 + b) * 128 + h];
    }
    if (tid < 8) nrm[tid] = 0.f;
    __syncthreads();

    for (int e = tid; e < 1024; e += 256) {
        int i = e >> 7, f = (e >> 4) & 7, s = e & 15;
        const float* rr = rep_p + ((size_t)f * 256 + b * 16 + s) * 128;
        float a = 0.f;
        for (int h = 0; h < 128; ++h) a += ZnL[i * 128 + h] * rr[h];
        sc[(i * 8 + f) * 16 + s] = a * rninv_p[f * 256 + b * 16 + s];
    }
    __syncthreads();
    if (tid < 64) {
        int i = tid >> 3, f = tid & 7;
        float aw[16];
        sparsemax16(&sc[(i * 8 + f) * 16], aw);
        for (int s = 0; s < 16; ++s) {
            sc[(i * 8 + f) * 16 + s] = aw[s];
            ibw_p[(((size_t)i * 8 + f) * 16 + b) * 16 + s] = aw[s];
        }
    }
    __syncthreads();
    if (pass == 0) {
        for (int e = tid; e < 1024; e += 256) {
            int i = e >> 7, h = e & 127;
            float u = 0.f;
            for (int f = 0; f < 8; ++f) {
                const float* rr = rep_p + ((size_t)f * 256 + b * 16) * 128 + h;
                const float* aa = &sc[(i * 8 + f) * 16];
                for (int s = 0; s < 16; ++s) u += aa[s] * rr[s * 128];
            }
            UL[e] = u * 0.125f;
        }
        __syncthreads();
        for (int e = tid; e < 1024; e += 256) {
            int f = e >> 7;
            float zz = ZnL[e], uu = UL[e];
            atomicAdd(&nrm[f], zz * zz + uu * uu);
        }
        __syncthreads();
        for (int e = tid; e < 2048; e += 256) {
            int f = e >> 8, d = e & 255;
            float inv = 1.f / fmaxf(sqrtf(nrm[f]), 1e-12f);
            float val = (d < 128 ? ZnL[f * 128 + d] : UL[f * 128 + d - 128]) * inv;
            float scv = g[e] * rsqrtf(vv[e] + 1e-5f);
            featbn[b * 2048 + e] = (val - mm[e]) * scv + bb[e];
        }
    }
}

// ---- dense head: bn(feat)@W1+b1, bn2, leaky, @W2+b2, softmax ---------------
__global__ __launch_bounds__(256) void k_head(
    const float* __restrict__ featbn,
    const float* __restrict__ W1, const float* __restrict__ b1,
    const float* __restrict__ g2, const float* __restrict__ bb2,
    const float* __restrict__ mm2, const float* __restrict__ vv2,
    const float* __restrict__ W2, const float* __restrict__ b2,
    float* __restrict__ ypred, float* __restrict__ dout)
{
    __shared__ float featL[2048], h2L[512], lgL[10];
    int tid = threadIdx.x, b = blockIdx.x;
    for (int i = tid; i < 2048; i += 256) featL[i] = featbn[b * 2048 + i];
    __syncthreads();
    for (int col = tid; col < 512; col += 256) {
        float a = b1[col];
        for (int c = 0; c < 2048; ++c) a += featL[c] * W1[(size_t)c * 512 + col];
        float scv = g2[col] * rsqrtf(vv2[col] + 1e-5f);
        float val = (a - mm2[col]) * scv + bb2[col];
        h2L[col] = lrelu(val);
    }
    __syncthreads();
    if (tid < 10) {
        float a = b2[tid];
        for (int c = 0; c < 512; ++c) a += h2L[c] * W2[c * 10 + tid];
        lgL[tid] = a;
    }
    __syncthreads();
    if (tid == 0) {
        float mx = lgL[0];
        for (int j = 1; j < 10; ++j) mx = fmaxf(mx, lgL[j]);
        float sum = 0.f, ex[10];
        for (int j = 0; j < 10; ++j) { ex[j] = expf(lgL[j] - mx); sum += ex[j]; }
        for (int j = 0; j < 10; ++j) {
            float p = ex[j] / sum;
            ypred[b * 10 + j] = p;
            dout[b * 10 + j] = p;
        }
    }
}

// ---- losses: MMD on intra/inter attention + CE on softmaxed preds ----------
__global__ __launch_bounds__(256) void k_loss(
    const float* __restrict__ sa, const float* __restrict__ ta,
    const float* __restrict__ sb, const float* __restrict__ tb,
    const float* __restrict__ ypred, const int* __restrict__ sy,
    float* __restrict__ dout)
{
    __shared__ float sA[8], sB[8];
    int tid = threadIdx.x;
    if (tid < 8) { sA[tid] = 0.f; sB[tid] = 0.f; }
    __syncthreads();
    if (tid < 128) {
        int f = tid >> 4, s = tid & 15;
        float d = 0.f;
        for (int b = 0; b < 16; ++b) d += sa[f * 256 + b * 16 + s] - ta[f * 256 + b * 16 + s];
        d *= (1.f / 16.f);
        atomicAdd(&sA[f], d * d);
    }
    for (int e = tid; e < 1024; e += 256) {
        int i = e >> 7, f = (e >> 4) & 7, s = e & 15;
        float d = 0.f;
        int base = ((i * 8 + f) * 16) * 16 + s;
        for (int b = 0; b < 16; ++b) d += sb[base + b * 16] - tb[base + b * 16];
        d *= (1.f / 16.f);
        atomicAdd(&sB[i], d * d);
    }
    __syncthreads();
    if (tid == 0) {
        float la = 0.f, lb = 0.f;
        for (int f = 0; f < 8; ++f) la += sqrtf(sA[f]);
        for (int i = 0; i < 8; ++i) lb += sqrtf(sB[i]);
        la *= 0.1f / 8.f;
        lb *= 0.1f / 8.f;
        float ce = 0.f;
        for (int b = 0; b < 16; ++b) {
            const float* y = ypred + b * 10;
            float mx = y[0];
            for (int j = 1; j < 10; ++j) mx = fmaxf(mx, y[j]);
            float sum = 0.f;
            for (int j = 0; j < 10; ++j) sum += expf(y[j] - mx);
            float lse = mx + logf(sum);
            ce += lse - y[sy[b]];
        }
        ce *= (1.f / 16.f);
        dout[160] = ce + la + lb;
    }
}

extern "C" void kernel_launch(void* const* d_in, const int* in_sizes, int n_in,
                              void* d_out, int out_size, void* d_ws, size_t ws_size,
                              hipStream_t stream) {
    (void)in_sizes; (void)n_in; (void)out_size; (void)ws_size;
    const float* src_x = (const float*)d_in[0];
    const int*   src_y = (const int*)d_in[1];
    const float* tgt_x = (const float*)d_in[2];
    const float *cw1 = (const float*)d_in[3], *bn1g = (const float*)d_in[4],
                *bn1b = (const float*)d_in[5], *bn1m = (const float*)d_in[6],
                *bn1v = (const float*)d_in[7];
    const float *cw2 = (const float*)d_in[8], *bn2g = (const float*)d_in[9],
                *bn2b = (const float*)d_in[10], *bn2m = (const float*)d_in[11],
                *bn2v = (const float*)d_in[12];
    const float *cw3 = (const float*)d_in[13], *bn3g = (const float*)d_in[14],
                *bn3b = (const float*)d_in[15], *bn3m = (const float*)d_in[16],
                *bn3v = (const float*)d_in[17];
    const float *Wq = (const float*)d_in[18], *bq = (const float*)d_in[19],
                *Wk = (const float*)d_in[20], *bk = (const float*)d_in[21],
                *Wv = (const float*)d_in[22], *bv = (const float*)d_in[23];
    const float *bc1g = (const float*)d_in[24], *bc1b = (const float*)d_in[25],
                *bc1m = (const float*)d_in[26], *bc1v = (const float*)d_in[27];
    const float *W1 = (const float*)d_in[28], *b1 = (const float*)d_in[29];
    const float *bc2g = (const float*)d_in[30], *bc2b = (const float*)d_in[31],
                *bc2m = (const float*)d_in[32], *bc2v = (const float*)d_in[33];
    const float *W2 = (const float*)d_in[34], *b2 = (const float*)d_in[35];

    float* ws = (float*)d_ws;
    size_t o = 0;
    float* rep    = ws + o; o += (size_t)2 * 262144;   // [pass][f,n,h]
    float* Zn     = ws + o; o += (size_t)2 * 16384;
    float* rninv  = ws + o; o += (size_t)2 * 2048;
    float* ia     = ws + o; o += (size_t)2 * 2048;
    float* ib     = ws + o; o += (size_t)2 * 16384;
    float* featbn = ws + o; o += (size_t)16 * 2048;
    float* ypred  = ws + o; o += 160;
    u16* wpk2 = (u16*)(ws + o); o += 65536;            // 131072 u16
    u16* wpk3 = (u16*)(ws + o); o += 262144;           // 524288 u16

    k_wprep<<<2560, 256, 0, stream>>>(cw2, cw3, wpk2, wpk3);
    k_cnn<<<4096, 256, 0, stream>>>(src_x, tgt_x,
        cw1, bn1g, bn1b, bn1m, bn1v,
        bn2g, bn2b, bn2m, bn2v,
        bn3g, bn3b, bn3m, bn3v,
        wpk2, wpk3, rep);
    k_attn1<<<256, 128, 0, stream>>>(rep, Wq, bq, Wk, bk, Wv, bv, Zn, rninv, ia);
    k_attn2<<<32, 256, 0, stream>>>(rep, Zn, rninv, ib, bc1g, bc1b, bc1m, bc1v, featbn);
    k_head<<<16, 256, 0, stream>>>(featbn, W1, b1, bc2g, bc2b, bc2m, bc2v, W2, b2,
                                   ypred, (float*)d_out);
    k_loss<<<1, 256, 0, stream>>>(ia, ia + 2048, ib, ib + 16384, ypred, src_y,
                                  (float*)d_out);
}

// Round 6
// 352.622 us; speedup vs baseline: 7.9659x; 1.2623x over previous
//
#include <hip/hip_runtime.h>

typedef unsigned short u16;
typedef unsigned int u32;
typedef __attribute__((ext_vector_type(8))) short bfrag;   // 8 bf16
typedef __attribute__((ext_vector_type(4))) float ffrag;   // 4 fp32 acc

__device__ __forceinline__ float lrelu(float x) { return x >= 0.f ? x : 0.01f * x; }
__device__ __forceinline__ float eluf(float x)  { return x > 0.f ? x : expm1f(x); }
__device__ __forceinline__ u16 f2bf(float f) {
    u32 x = __float_as_uint(f);
    return (u16)((x + 0x7fffu + ((x >> 16) & 1u)) >> 16);
}
__device__ __forceinline__ float bf2f(u16 u) {
    return __uint_as_float(((u32)u) << 16);
}

// sparsemax over 16 elements (Martins & Astudillo), exact ksup-count semantics
__device__ void sparsemax16(const float* z, float* out) {
    float zs[16];
    for (int i = 0; i < 16; ++i) zs[i] = z[i];
    for (int i = 1; i < 16; ++i) {
        float key = zs[i]; int j = i - 1;
        while (j >= 0 && zs[j] < key) { zs[j + 1] = zs[j]; --j; }
        zs[j + 1] = key;
    }
    float cum[16];
    cum[0] = zs[0];
    for (int i = 1; i < 16; ++i) cum[i] = cum[i - 1] + zs[i];
    int ksup = 0;
    for (int k = 1; k <= 16; ++k)
        if (1.0f + (float)k * zs[k - 1] > cum[k - 1]) ksup++;
    if (ksup < 1) ksup = 1;
    float tau = (cum[ksup - 1] - 1.0f) / (float)ksup;
    for (int i = 0; i < 16; ++i) out[i] = fmaxf(z[i] - tau, 0.0f);
}

// ---- weight pre-pack into B-fragment order (bf16) --------------------------
__global__ __launch_bounds__(256) void k_wprep(
    const float* __restrict__ w2, const float* __restrict__ w3,
    u16* __restrict__ wpk2, u16* __restrict__ wpk3)
{
    int i = blockIdx.x * 256 + threadIdx.x;
    if (i < 131072) {
        int j = i & 7, L = (i >> 3) & 63, kc = (i >> 9) & 7, nt = (i >> 12) & 3, f = i >> 14;
        int co = nt * 16 + (L & 15);
        int ci = ((L >> 4) << 3) + j;
        wpk2[i] = f2bf(w2[(((size_t)f * 64 + co) * 32 + ci) * 8 + kc]);
    } else if (i < 131072 + 524288) {
        int i2 = i - 131072;
        int j = i2 & 7, L = (i2 >> 3) & 63, kc = (i2 >> 9) & 15, nt = (i2 >> 13) & 7, f = i2 >> 16;
        int co = nt * 16 + (L & 15);
        int ci = ((kc & 1) << 5) + ((L >> 4) << 3) + j;
        wpk3[i2] = f2bf(w3[(((size_t)f * 128 + co) * 64 + ci) * 8 + (kc >> 1)]);
    }
}

// ===== fused CNN (both passes): conv1 fp32 -> conv2/conv3 bf16 MFMA ==========
#define S1T_STRIDE 40
#define S2T_STRIDE 72
#define RB_OFF 6336
#define SMEM_U16 15448

__global__ __launch_bounds__(256) void k_cnn(
    const float* __restrict__ xs, const float* __restrict__ xt,
    const float* __restrict__ w1, const float* __restrict__ g1, const float* __restrict__ b1,
    const float* __restrict__ m1, const float* __restrict__ v1,
    const float* __restrict__ g2, const float* __restrict__ b2,
    const float* __restrict__ m2, const float* __restrict__ v2,
    const float* __restrict__ g3, const float* __restrict__ b3,
    const float* __restrict__ m3, const float* __restrict__ v3,
    const u16* __restrict__ wpk2, const u16* __restrict__ wpk3,
    float* __restrict__ rep)
{
    __shared__ __align__(16) u16 smem[SMEM_U16];
    float* xin = (float*)(smem + RB_OFF);      // 264 floats

    int tid = threadIdx.x, blk = blockIdx.x;
    int pass = blk >> 11, f = (blk >> 8) & 7, n = blk & 255;
    int bb = n >> 4, ss = n & 15;
    int lane = tid & 63, w = tid >> 6;
    const float* x = pass ? xt : xs;
    float* rep_p = rep + (size_t)pass * 262144;

    {
        u32* z = (u32*)smem;
        for (int i = tid; i < 3168; i += 256) z[i] = 0;
        for (int i = tid; i < 264; i += 256) xin[i] = 0.f;
    }
    __syncthreads();
    {
        const float* xr = x + (((size_t)bb * 8 + f) * 16 + ss) * 256;
        for (int i = tid; i < 256; i += 256) xin[i + 4] = xr[i];
    }
    __syncthreads();

    // ---- conv1 fp32 (1->32, 256 -> conv 257 -> pool 129) ----
    if (tid < 208) {
        int cc = tid & 7, jc = tid >> 3;
        int co0 = cc * 4, j0 = jc * 5;
        float wr[4][8];
        for (int c = 0; c < 4; ++c) {
            const float4* q = reinterpret_cast<const float4*>(w1 + ((size_t)f * 32 + co0 + c) * 8);
            float4 a = q[0], bq = q[1];
            wr[c][0] = a.x; wr[c][1] = a.y; wr[c][2] = a.z; wr[c][3] = a.w;
            wr[c][4] = bq.x; wr[c][5] = bq.y; wr[c][6] = bq.z; wr[c][7] = bq.w;
        }
        int px[10];
        for (int i = 0; i < 10; ++i) {
            int p = 2 * j0 - 1 + i;
            px[i] = p < 0 ? 0 : (p > 256 ? 256 : p);
        }
        float acc[4][10];
        for (int c = 0; c < 4; ++c) for (int i = 0; i < 10; ++i) acc[c][i] = 0.f;
        for (int k = 0; k < 8; ++k) {
            float xv[10];
            for (int i = 0; i < 10; ++i) xv[i] = xin[px[i] + k];
            for (int c = 0; c < 4; ++c)
                for (int i = 0; i < 10; ++i) acc[c][i] += wr[c][k] * xv[i];
        }
        for (int c = 0; c < 4; ++c) {
            int co = co0 + c;
            float sc = g1[f * 32 + co] * rsqrtf(v1[f * 32 + co] + 1e-5f);
            float sh = b1[f * 32 + co] - m1[f * 32 + co] * sc;
            for (int jj = 0; jj < 5; ++jj) {
                int j = j0 + jj;
                if (j < 129) {
                    float a0 = fmaxf(acc[c][2 * jj] * sc + sh, 0.f);
                    float a1 = fmaxf(acc[c][2 * jj + 1] * sc + sh, 0.f);
                    smem[(j + 4) * S1T_STRIDE + co] = f2bf(fmaxf(a0, a1));
                }
            }
        }
    }
    __syncthreads();

    // ---- conv2 MFMA (M=130 pos, N=64 co, K=256) ----
    {
        int nt = w;
        bfrag B2[8];
        const bfrag* gB = reinterpret_cast<const bfrag*>(wpk2);
        for (int kc = 0; kc < 8; ++kc)
            B2[kc] = gB[(((size_t)f * 4 + nt) * 8 + kc) * 64 + lane];
        int co = nt * 16 + (lane & 15);
        float sc = g2[f * 64 + co] * rsqrtf(v2[f * 64 + co] + 1e-5f);
        float sh = b2[f * 64 + co] - m2[f * 64 + co] * sc;
        int arow = lane & 15, ci0 = (lane >> 4) << 3;
        for (int mt = 0; mt < 9; ++mt) {
            ffrag C = {0.f, 0.f, 0.f, 0.f};
            int rb = mt * 16 + arow;
            for (int kc = 0; kc < 8; ++kc) {
                bfrag A = *reinterpret_cast<const bfrag*>(&smem[(rb + kc) * S1T_STRIDE + ci0]);
                C = __builtin_amdgcn_mfma_f32_16x16x32_bf16(A, B2[kc], C, 0, 0, 0);
            }
            int p0 = mt * 16 + ((lane >> 4) << 2);
            for (int r = 0; r < 4; ++r) {
                int p = p0 + r;
                if (p < 130)
                    smem[RB_OFF + p * 64 + co] = f2bf(fmaxf(C[r] * sc + sh, 0.f));
            }
        }
    }
    __syncthreads();

    {
        u32* z = (u32*)smem;
        for (int i = tid; i < 3168; i += 256) z[i] = 0;
    }
    __syncthreads();

    // ---- pool conv2 -> s2T ----
    for (int e = tid; e < 66 * 64; e += 256) {
        int j = e >> 6, ci = e & 63;
        float vmax;
        if (j == 0) {
            vmax = bf2f(smem[RB_OFF + 0 * 64 + ci]);
        } else if (j == 65) {
            vmax = bf2f(smem[RB_OFF + 129 * 64 + ci]);
        } else {
            float a0 = bf2f(smem[RB_OFF + (2 * j - 1) * 64 + ci]);
            float a1 = bf2f(smem[RB_OFF + (2 * j) * 64 + ci]);
            vmax = fmaxf(a0, a1);
        }
        smem[(j + 4) * S2T_STRIDE + ci] = f2bf(vmax);
    }
    __syncthreads();

    // ---- conv3 MFMA (M=67 pos, N=128 co, K=512) ----
    for (int t = 0; t < 2; ++t) {
        int nt = w * 2 + t;
        bfrag B3[16];
        const bfrag* gB = reinterpret_cast<const bfrag*>(wpk3);
        for (int kc = 0; kc < 16; ++kc)
            B3[kc] = gB[(((size_t)f * 8 + nt) * 16 + kc) * 64 + lane];
        int co = nt * 16 + (lane & 15);
        float sc = g3[f * 128 + co] * rsqrtf(v3[f * 128 + co] + 1e-5f);
        float sh = b3[f * 128 + co] - m3[f * 128 + co] * sc;
        int arow = lane & 15, q8 = (lane >> 4) << 3;
        for (int mt = 0; mt < 5; ++mt) {
            ffrag C = {0.f, 0.f, 0.f, 0.f};
            int rb = mt * 16 + arow;
            for (int kc = 0; kc < 16; ++kc) {
                int row = rb + (kc >> 1);
                int ci0 = ((kc & 1) << 5) + q8;
                bfrag A = *reinterpret_cast<const bfrag*>(&smem[row * S2T_STRIDE + ci0]);
                C = __builtin_amdgcn_mfma_f32_16x16x32_bf16(A, B3[kc], C, 0, 0, 0);
            }
            int p0 = mt * 16 + ((lane >> 4) << 2);
            for (int r = 0; r < 4; ++r) {
                int p = p0 + r;
                if (p < 67)
                    smem[RB_OFF + p * 136 + co] = f2bf(fmaxf(C[r] * sc + sh, 0.f));
            }
        }
    }
    __syncthreads();

    // ---- pool conv3 + mean -> rep ----
    if (tid < 128) {
        int co = tid;
        float sum = bf2f(smem[RB_OFF + 0 * 136 + co]);
        for (int j = 1; j < 34; ++j) {
            float a0 = bf2f(smem[RB_OFF + (2 * j - 1) * 136 + co]);
            float a1 = bf2f(smem[RB_OFF + (2 * j) * 136 + co]);
            sum += fmaxf(a0, a1);
        }
        rep_p[(((size_t)f * 256) + n) * 128 + co] = sum * (1.0f / 34.0f);
    }
}

// ---- QKV + scores + intra sparsemax + Z(normalized) + rep inv-norms --------
__global__ __launch_bounds__(128) void k_attn1(
    const float* __restrict__ rep,
    const float* __restrict__ Wq, const float* __restrict__ bq,
    const float* __restrict__ Wk, const float* __restrict__ bk,
    const float* __restrict__ Wv, const float* __restrict__ bv,
    float* __restrict__ Zn, float* __restrict__ rninv, float* __restrict__ iaw)
{
    __shared__ float repL[2048], QL[2048], VL[2048];
    __shared__ float KmL[128], red[128], scoresL[16], awL[16];
    int tid = threadIdx.x;
    int pass = blockIdx.x >> 7, f = (blockIdx.x >> 4) & 7, b = blockIdx.x & 15;
    const float* rep_p = rep + (size_t)pass * 262144;
    float* Zn_p = Zn + (size_t)pass * 16384;
    float* rninv_p = rninv + (size_t)pass * 2048;
    float* iaw_p = iaw + (size_t)pass * 2048;

    const float* rb = rep_p + ((size_t)f * 256 + b * 16) * 128;
    for (int i = tid; i < 2048; i += 128) repL[i] = rb[i];
    __syncthreads();

    int h2 = tid;
    float km = 0.f;
    float bqv = bq[h2], bkv = bk[h2], bvv = bv[h2];
    for (int s0 = 0; s0 < 16; s0 += 8) {
        float aq[8], ak[8], av[8];
        for (int t = 0; t < 8; ++t) { aq[t] = bqv; ak[t] = bkv; av[t] = bvv; }
        for (int h = 0; h < 128; ++h) {
            float wq = Wq[h * 128 + h2];
            float wk = Wk[h * 128 + h2];
            float wv = Wv[h * 128 + h2];
            for (int t = 0; t < 8; ++t) {
                float r = repL[(s0 + t) * 128 + h];
                aq[t] += r * wq; ak[t] += r * wk; av[t] += r * wv;
            }
        }
        for (int t = 0; t < 8; ++t) {
            QL[(s0 + t) * 128 + h2] = eluf(aq[t]);
            VL[(s0 + t) * 128 + h2] = lrelu(av[t]);
            km += lrelu(ak[t]);
        }
    }
    KmL[h2] = km * (1.f / 16.f);
    __syncthreads();

    if (tid < 16) {
        float a = 0.f;
        for (int h = 0; h < 128; ++h) a += QL[tid * 128 + h] * KmL[h];
        scoresL[tid] = a * 0.08838834764831845f;   // 1/sqrt(128)
        float r2 = 0.f;
        for (int h = 0; h < 128; ++h) { float r = repL[tid * 128 + h]; r2 += r * r; }
        rninv_p[f * 256 + b * 16 + tid] = 1.f / fmaxf(sqrtf(r2), 1e-12f);
    }
    __syncthreads();
    if (tid == 0) sparsemax16(scoresL, awL);
    __syncthreads();
    if (tid < 16) iaw_p[f * 256 + b * 16 + tid] = awL[tid];

    float z = 0.f;
    for (int s = 0; s < 16; ++s) z += awL[s] * VL[s * 128 + tid];
    red[tid] = z * z;
    __syncthreads();
    for (int st = 64; st > 0; st >>= 1) {
        if (tid < st) red[tid] += red[tid + st];
        __syncthreads();
    }
    float inv = 1.f / fmaxf(sqrtf(red[0]), 1e-12f);
    Zn_p[((size_t)f * 16 + b) * 128 + tid] = z * inv;
}

// ---- inter scores + sparsemax + U + Hc + BN(feat) --------------------------
__global__ __launch_bounds__(256) void k_attn2(
    const float* __restrict__ rep, const float* __restrict__ Zn,
    const float* __restrict__ rninv, float* __restrict__ ibw,
    const float* __restrict__ g, const float* __restrict__ bb,
    const float* __restrict__ mm, const float* __restrict__ vv,
    float* __restrict__ featbn)
{
    __shared__ float ZnL[1024], sc[1024], UL[1024], nrm[8];
    int tid = threadIdx.x;
    int pass = blockIdx.x >> 4, b = blockIdx.x & 15;
    const float* rep_p = rep + (size_t)pass * 262144;
    const float* Zn_p = Zn + (size_t)pass * 16384;
    const float* rninv_p = rninv + (size_t)pass * 2048;
    float* ibw_p = ibw + (size_t)pass * 16384;

    for (int i = tid; i < 1024; i += 256) {
        int ii = i >> 7, h = i & 127;
        ZnL[i] = Zn_p[((size_t)ii * 16 + b) * 128 + h];
    }
    if (tid < 8) nrm[tid] = 0.f;
    __syncthreads();

    for (int e = tid; e < 1024; e += 256) {
        int i = e >> 7, f = (e >> 4) & 7, s = e & 15;
        const float* rr = rep_p + ((size_t)f * 256 + b * 16 + s) * 128;
        float a = 0.f;
        for (int h = 0; h < 128; ++h) a += ZnL[i * 128 + h] * rr[h];
        sc[(i * 8 + f) * 16 + s] = a * rninv_p[f * 256 + b * 16 + s];
    }
    __syncthreads();
    if (tid < 64) {
        int i = tid >> 3, f = tid & 7;
        float aw[16];
        sparsemax16(&sc[(i * 8 + f) * 16], aw);
        for (int s = 0; s < 16; ++s) {
            sc[(i * 8 + f) * 16 + s] = aw[s];
            ibw_p[(((size_t)i * 8 + f) * 16 + b) * 16 + s] = aw[s];
        }
    }
    __syncthreads();
    if (pass == 0) {
        for (int e = tid; e < 1024; e += 256) {
            int i = e >> 7, h = e & 127;
            float u = 0.f;
            for (int f = 0; f < 8; ++f) {
                const float* rr = rep_p + ((size_t)f * 256 + b * 16) * 128 + h;
                const float* aa = &sc[(i * 8 + f) * 16];
                for (int s = 0; s < 16; ++s) u += aa[s] * rr[s * 128];
            }
            UL[e] = u * 0.125f;
        }
        __syncthreads();
        for (int e = tid; e < 1024; e += 256) {
            int f = e >> 7;
            float zz = ZnL[e], uu = UL[e];
            atomicAdd(&nrm[f], zz * zz + uu * uu);
        }
        __syncthreads();
        for (int e = tid; e < 2048; e += 256) {
            int f = e >> 8, d = e & 255;
            float inv = 1.f / fmaxf(sqrtf(nrm[f]), 1e-12f);
            float val = (d < 128 ? ZnL[f * 128 + d] : UL[f * 128 + d - 128]) * inv;
            float scv = g[e] * rsqrtf(vv[e] + 1e-5f);
            featbn[b * 2048 + e] = (val - mm[e]) * scv + bb[e];
        }
    }
}

// ---- head stage 1: bn(feat)@W1+b1 -> bn2 -> lrelu -> h2ws[16][512] ---------
// grid 256 = b*16+cc; blocks sharing cc land on the same XCD (idx%8==cc%8)
// so each W1 column-chunk is HBM-fetched once and L2-served 15 times.
__global__ __launch_bounds__(256) void k_head1(
    const float* __restrict__ featbn,
    const float* __restrict__ W1, const float* __restrict__ b1,
    const float* __restrict__ g2, const float* __restrict__ bb2,
    const float* __restrict__ mm2, const float* __restrict__ vv2,
    float* __restrict__ h2ws)
{
    __shared__ float featL[2048];
    __shared__ float part[8][32];
    int tid = threadIdx.x, blk = blockIdx.x;
    int b = blk >> 4, cc = blk & 15;
    for (int i = tid; i < 2048; i += 256) featL[i] = featbn[b * 2048 + i];
    __syncthreads();
    int ci = tid & 31, ks = tid >> 5;
    int col = cc * 32 + ci;
    const float* wcol = W1 + (size_t)(ks * 256) * 512 + col;
    const float* fl = featL + ks * 256;
    float a = 0.f;
    for (int c = 0; c < 256; ++c) a += fl[c] * wcol[(size_t)c * 512];
    part[ks][ci] = a;
    __syncthreads();
    if (tid < 32) {
        int colw = cc * 32 + tid;
        float s = b1[colw];
        for (int k2 = 0; k2 < 8; ++k2) s += part[k2][tid];
        float scv = g2[colw] * rsqrtf(vv2[colw] + 1e-5f);
        float val = (s - mm2[colw]) * scv + bb2[colw];
        h2ws[b * 512 + colw] = lrelu(val);
    }
}

// ---- tail: h2 @ W2 + b2, softmax -> dout[0:160]; MMD + CE -> dout[160] -----
__global__ __launch_bounds__(256) void k_tail(
    const float* __restrict__ h2ws,
    const float* __restrict__ W2, const float* __restrict__ b2,
    const float* __restrict__ sa, const float* __restrict__ ta,
    const float* __restrict__ sb, const float* __restrict__ tb,
    const int* __restrict__ sy, float* __restrict__ dout)
{
    __shared__ float h2L[8192];
    __shared__ float lgL[160], ypL[160];
    __shared__ float sA[8], sB[8];
    int tid = threadIdx.x;
    for (int i = tid; i < 8192; i += 256) h2L[i] = h2ws[i];
    if (tid < 8) { sA[tid] = 0.f; sB[tid] = 0.f; }
    __syncthreads();
    if (tid < 160) {
        int b = tid / 10, j = tid - b * 10;
        float a = b2[j];
        const float* h = h2L + b * 512;
        for (int c = 0; c < 512; ++c) a += h[c] * W2[c * 10 + j];
        lgL[tid] = a;
    }
    __syncthreads();
    if (tid < 16) {
        int b = tid;
        float mx = lgL[b * 10];
        for (int j = 1; j < 10; ++j) mx = fmaxf(mx, lgL[b * 10 + j]);
        float sum = 0.f, ex[10];
        for (int j = 0; j < 10; ++j) { ex[j] = expf(lgL[b * 10 + j] - mx); sum += ex[j]; }
        for (int j = 0; j < 10; ++j) {
            float p = ex[j] / sum;
            ypL[b * 10 + j] = p;
            dout[b * 10 + j] = p;
        }
    }
    __syncthreads();
    if (tid < 128) {
        int f = tid >> 4, s = tid & 15;
        float d = 0.f;
        for (int b = 0; b < 16; ++b) d += sa[f * 256 + b * 16 + s] - ta[f * 256 + b * 16 + s];
        d *= (1.f / 16.f);
        atomicAdd(&sA[f], d * d);
    }
    for (int e = tid; e < 1024; e += 256) {
        int i = e >> 7, f = (e >> 4) & 7, s = e & 15;
        float d = 0.f;
        int base = ((i * 8 + f) * 16) * 16 + s;
        for (int b = 0; b < 16; ++b) d += sb[base + b * 16] - tb[base + b * 16];
        d *= (1.f / 16.f);
        atomicAdd(&sB[i], d * d);
    }
    __syncthreads();
    if (tid == 0) {
        float la = 0.f, lb = 0.f;
        for (int f = 0; f < 8; ++f) la += sqrtf(sA[f]);
        for (int i = 0; i < 8; ++i) lb += sqrtf(sB[i]);
        la *= 0.1f / 8.f;
        lb *= 0.1f / 8.f;
        float ce = 0.f;
        for (int b = 0; b < 16; ++b) {
            const float* y = ypL + b * 10;
            float mx = y[0];
            for (int j = 1; j < 10; ++j) mx = fmaxf(mx, y[j]);
            float sum = 0.f;
            for (int j = 0; j < 10; ++j) sum += expf(y[j] - mx);
            float lse = mx + logf(sum);
            ce += lse - y[sy[b]];
        }
        ce *= (1.f / 16.f);
        dout[160] = ce + la + lb;
    }
}

extern "C" void kernel_launch(void* const* d_in, const int* in_sizes, int n_in,
                              void* d_out, int out_size, void* d_ws, size_t ws_size,
                              hipStream_t stream) {
    (void)in_sizes; (void)n_in; (void)out_size; (void)ws_size;
    const float* src_x = (const float*)d_in[0];
    const int*   src_y = (const int*)d_in[1];
    const float* tgt_x = (const float*)d_in[2];
    const float *cw1 = (const float*)d_in[3], *bn1g = (const float*)d_in[4],
                *bn1b = (const float*)d_in[5], *bn1m = (const float*)d_in[6],
                *bn1v = (const float*)d_in[7];
    const float *cw2 = (const float*)d_in[8], *bn2g = (const float*)d_in[9],
                *bn2b = (const float*)d_in[10], *bn2m = (const float*)d_in[11],
                *bn2v = (const float*)d_in[12];
    const float *cw3 = (const float*)d_in[13], *bn3g = (const float*)d_in[14],
                *bn3b = (const float*)d_in[15], *bn3m = (const float*)d_in[16],
                *bn3v = (const float*)d_in[17];
    const float *Wq = (const float*)d_in[18], *bq = (const float*)d_in[19],
                *Wk = (const float*)d_in[20], *bk = (const float*)d_in[21],
                *Wv = (const float*)d_in[22], *bv = (const float*)d_in[23];
    const float *bc1g = (const float*)d_in[24], *bc1b = (const float*)d_in[25],
                *bc1m = (const float*)d_in[26], *bc1v = (const float*)d_in[27];
    const float *W1 = (const float*)d_in[28], *b1 = (const float*)d_in[29];
    const float *bc2g = (const float*)d_in[30], *bc2b = (const float*)d_in[31],
                *bc2m = (const float*)d_in[32], *bc2v = (const float*)d_in[33];
    const float *W2 = (const float*)d_in[34], *b2 = (const float*)d_in[35];

    float* ws = (float*)d_ws;
    size_t o = 0;
    float* rep    = ws + o; o += (size_t)2 * 262144;   // [pass][f,n,h]
    float* Zn     = ws + o; o += (size_t)2 * 16384;
    float* rninv  = ws + o; o += (size_t)2 * 2048;
    float* ia     = ws + o; o += (size_t)2 * 2048;
    float* ib     = ws + o; o += (size_t)2 * 16384;
    float* featbn = ws + o; o += (size_t)16 * 2048;
    float* h2ws   = ws + o; o += (size_t)16 * 512;
    u16* wpk2 = (u16*)(ws + o); o += 65536;            // 131072 u16
    u16* wpk3 = (u16*)(ws + o); o += 262144;           // 524288 u16

    k_wprep<<<2560, 256, 0, stream>>>(cw2, cw3, wpk2, wpk3);
    k_cnn<<<4096, 256, 0, stream>>>(src_x, tgt_x,
        cw1, bn1g, bn1b, bn1m, bn1v,
        bn2g, bn2b, bn2m, bn2v,
        bn3g, bn3b, bn3m, bn3v,
        wpk2, wpk3, rep);
    k_attn1<<<256, 128, 0, stream>>>(rep, Wq, bq, Wk, bk, Wv, bv, Zn, rninv, ia);
    k_attn2<<<32, 256, 0, stream>>>(rep, Zn, rninv, ib, bc1g, bc1b, bc1m, bc1v, featbn);
    k_head1<<<256, 256, 0, stream>>>(featbn, W1, b1, bc2g, bc2b, bc2m, bc2v, h2ws);
    k_tail<<<1, 256, 0, stream>>>(h2ws, W2, b2, ia, ia + 2048, ib, ib + 16384,
                                  src_y, (float*)d_out);
}

// Round 7
// 333.175 us; speedup vs baseline: 8.4309x; 1.0584x over previous
//
#include <hip/hip_runtime.h>

typedef unsigned short u16;
typedef unsigned int u32;
typedef __attribute__((ext_vector_type(8))) short bfrag;   // 8 bf16
typedef __attribute__((ext_vector_type(4))) float ffrag;   // 4 fp32 acc

__device__ __forceinline__ float lrelu(float x) { return x >= 0.f ? x : 0.01f * x; }
__device__ __forceinline__ float eluf(float x)  { return x > 0.f ? x : expm1f(x); }
__device__ __forceinline__ u16 f2bf(float f) {            // RNE (used in wprep only)
    u32 x = __float_as_uint(f);
    return (u16)((x + 0x7fffu + ((x >> 16) & 1u)) >> 16);
}
__device__ __forceinline__ u16 f2bt(float f) {            // truncate (internal roundtrips)
    return (u16)(__float_as_uint(f) >> 16);
}
__device__ __forceinline__ float bf2f(u16 u) {
    return __uint_as_float(((u32)u) << 16);
}

// sparsemax over 16 elements (Martins & Astudillo), exact ksup-count semantics
__device__ void sparsemax16(const float* z, float* out) {
    float zs[16];
    for (int i = 0; i < 16; ++i) zs[i] = z[i];
    for (int i = 1; i < 16; ++i) {
        float key = zs[i]; int j = i - 1;
        while (j >= 0 && zs[j] < key) { zs[j + 1] = zs[j]; --j; }
        zs[j + 1] = key;
    }
    float cum[16];
    cum[0] = zs[0];
    for (int i = 1; i < 16; ++i) cum[i] = cum[i - 1] + zs[i];
    int ksup = 0;
    for (int k = 1; k <= 16; ++k)
        if (1.0f + (float)k * zs[k - 1] > cum[k - 1]) ksup++;
    if (ksup < 1) ksup = 1;
    float tau = (cum[ksup - 1] - 1.0f) / (float)ksup;
    for (int i = 0; i < 16; ++i) out[i] = fmaxf(z[i] - tau, 0.0f);
}

// ---- weight pre-pack into B-fragment order (bf16) --------------------------
// wpk2: 131072, wpk3: 524288, wqkv: 3*16384 (Wq/Wk/Wv, [nt:8][kc:4][lane:64][j:8])
__global__ __launch_bounds__(256) void k_wprep(
    const float* __restrict__ w2, const float* __restrict__ w3,
    const float* __restrict__ Wq, const float* __restrict__ Wk,
    const float* __restrict__ Wv,
    u16* __restrict__ wpk2, u16* __restrict__ wpk3, u16* __restrict__ wqkv)
{
    int i = blockIdx.x * 256 + threadIdx.x;
    if (i < 131072) {
        int j = i & 7, L = (i >> 3) & 63, kc = (i >> 9) & 7, nt = (i >> 12) & 3, f = i >> 14;
        int co = nt * 16 + (L & 15);
        int ci = ((L >> 4) << 3) + j;
        wpk2[i] = f2bf(w2[(((size_t)f * 64 + co) * 32 + ci) * 8 + kc]);
    } else if (i < 131072 + 524288) {
        int i2 = i - 131072;
        int j = i2 & 7, L = (i2 >> 3) & 63, kc = (i2 >> 9) & 15, nt = (i2 >> 13) & 7, f = i2 >> 16;
        int co = nt * 16 + (L & 15);
        int ci = ((kc & 1) << 5) + ((L >> 4) << 3) + j;
        wpk3[i2] = f2bf(w3[(((size_t)f * 128 + co) * 64 + ci) * 8 + (kc >> 1)]);
    } else if (i < 131072 + 524288 + 49152) {
        int j2 = i - 655360;
        int proj = j2 >> 14, idx = j2 & 16383;
        int jj = idx & 7, L = (idx >> 3) & 63, kc = (idx >> 9) & 3, nt = idx >> 11;
        int n = nt * 16 + (L & 15);
        int k = kc * 32 + ((L >> 4) << 3) + jj;
        const float* W = proj == 0 ? Wq : (proj == 1 ? Wk : Wv);
        wqkv[j2] = f2bf(W[k * 128 + n]);
    }
}

// ===== fused CNN (both passes): conv1 fp32 -> conv2/conv3 bf16 MFMA ==========
#define S1T_STRIDE 40
#define S2T_STRIDE 72
#define RB2_STRIDE 68
#define RB3_STRIDE 140
#define RB_OFF 6336
#define SMEM_U16 (RB_OFF + 67 * RB3_STRIDE)   // 6336 + 9380 = 15716

__global__ __launch_bounds__(256) void k_cnn(
    const float* __restrict__ xs, const float* __restrict__ xt,
    const float* __restrict__ w1, const float* __restrict__ g1, const float* __restrict__ b1,
    const float* __restrict__ m1, const float* __restrict__ v1,
    const float* __restrict__ g2, const float* __restrict__ b2,
    const float* __restrict__ m2, const float* __restrict__ v2,
    const float* __restrict__ g3, const float* __restrict__ b3,
    const float* __restrict__ m3, const float* __restrict__ v3,
    const u16* __restrict__ wpk2, const u16* __restrict__ wpk3,
    float* __restrict__ rep)
{
    __shared__ __align__(16) u16 smem[SMEM_U16];
    float* xin = (float*)(smem + RB_OFF);      // 264 floats

    int tid = threadIdx.x, blk = blockIdx.x;
    int pass = blk >> 11, f = (blk >> 8) & 7, n = blk & 255;
    int bb = n >> 4, ss = n & 15;
    int lane = tid & 63, w = tid >> 6;
    const float* x = pass ? xt : xs;
    float* rep_p = rep + (size_t)pass * 262144;

    {
        u32* z = (u32*)smem;
        for (int i = tid; i < 3168; i += 256) z[i] = 0;
        for (int i = tid; i < 264; i += 256) xin[i] = 0.f;
    }
    __syncthreads();
    {
        const float* xr = x + (((size_t)bb * 8 + f) * 16 + ss) * 256;
        for (int i = tid; i < 256; i += 256) xin[i + 4] = xr[i];
    }
    __syncthreads();

    // ---- conv1 fp32 (1->32, 256 -> conv 257 -> pool 129) ----
    if (tid < 208) {
        int cc = tid & 7, jc = tid >> 3;
        int co0 = cc * 4, j0 = jc * 5;
        float wr[4][8];
        for (int c = 0; c < 4; ++c) {
            const float4* q = reinterpret_cast<const float4*>(w1 + ((size_t)f * 32 + co0 + c) * 8);
            float4 a = q[0], bq = q[1];
            wr[c][0] = a.x; wr[c][1] = a.y; wr[c][2] = a.z; wr[c][3] = a.w;
            wr[c][4] = bq.x; wr[c][5] = bq.y; wr[c][6] = bq.z; wr[c][7] = bq.w;
        }
        int px[10];
        for (int i = 0; i < 10; ++i) {
            int p = 2 * j0 - 1 + i;
            px[i] = p < 0 ? 0 : (p > 256 ? 256 : p);
        }
        float acc[4][10];
        for (int c = 0; c < 4; ++c) for (int i = 0; i < 10; ++i) acc[c][i] = 0.f;
        for (int k = 0; k < 8; ++k) {
            float xv[10];
            for (int i = 0; i < 10; ++i) xv[i] = xin[px[i] + k];
            for (int c = 0; c < 4; ++c)
                for (int i = 0; i < 10; ++i) acc[c][i] += wr[c][k] * xv[i];
        }
        for (int c = 0; c < 4; ++c) {
            int co = co0 + c;
            float sc = g1[f * 32 + co] * rsqrtf(v1[f * 32 + co] + 1e-5f);
            float sh = b1[f * 32 + co] - m1[f * 32 + co] * sc;
            for (int jj = 0; jj < 5; ++jj) {
                int j = j0 + jj;
                if (j < 129) {
                    float a0 = fmaxf(acc[c][2 * jj] * sc + sh, 0.f);
                    float a1 = fmaxf(acc[c][2 * jj + 1] * sc + sh, 0.f);
                    smem[(j + 4) * S1T_STRIDE + co] = f2bt(fmaxf(a0, a1));
                }
            }
        }
    }
    __syncthreads();

    // ---- conv2 MFMA (M=130 pos, N=64 co, K=256) ----
    {
        int nt = w;
        bfrag B2[8];
        const bfrag* gB = reinterpret_cast<const bfrag*>(wpk2);
        for (int kc = 0; kc < 8; ++kc)
            B2[kc] = gB[(((size_t)f * 4 + nt) * 8 + kc) * 64 + lane];
        int co = nt * 16 + (lane & 15);
        float sc = g2[f * 64 + co] * rsqrtf(v2[f * 64 + co] + 1e-5f);
        float sh = b2[f * 64 + co] - m2[f * 64 + co] * sc;
        int arow = lane & 15, ci0 = (lane >> 4) << 3;
        for (int mt = 0; mt < 9; ++mt) {
            ffrag C = {0.f, 0.f, 0.f, 0.f};
            int rb = mt * 16 + arow;
            for (int kc = 0; kc < 8; ++kc) {
                bfrag A = *reinterpret_cast<const bfrag*>(&smem[(rb + kc) * S1T_STRIDE + ci0]);
                C = __builtin_amdgcn_mfma_f32_16x16x32_bf16(A, B2[kc], C, 0, 0, 0);
            }
            int p0 = mt * 16 + ((lane >> 4) << 2);
            for (int r = 0; r < 4; ++r) {
                int p = p0 + r;
                if (p < 130)
                    smem[RB_OFF + p * RB2_STRIDE + co] = f2bt(fmaxf(C[r] * sc + sh, 0.f));
            }
        }
    }
    __syncthreads();

    {
        u32* z = (u32*)smem;
        for (int i = tid; i < 3168; i += 256) z[i] = 0;
    }
    __syncthreads();

    // ---- pool conv2 -> s2T ----
    for (int e = tid; e < 66 * 64; e += 256) {
        int j = e >> 6, ci = e & 63;
        float vmax;
        if (j == 0) {
            vmax = bf2f(smem[RB_OFF + 0 * RB2_STRIDE + ci]);
        } else if (j == 65) {
            vmax = bf2f(smem[RB_OFF + 129 * RB2_STRIDE + ci]);
        } else {
            float a0 = bf2f(smem[RB_OFF + (2 * j - 1) * RB2_STRIDE + ci]);
            float a1 = bf2f(smem[RB_OFF + (2 * j) * RB2_STRIDE + ci]);
            vmax = fmaxf(a0, a1);
        }
        smem[(j + 4) * S2T_STRIDE + ci] = f2bt(vmax);
    }
    __syncthreads();

    // ---- conv3 MFMA (M=67 pos, N=128 co, K=512) ----
    for (int t = 0; t < 2; ++t) {
        int nt = w * 2 + t;
        bfrag B3[16];
        const bfrag* gB = reinterpret_cast<const bfrag*>(wpk3);
        for (int kc = 0; kc < 16; ++kc)
            B3[kc] = gB[(((size_t)f * 8 + nt) * 16 + kc) * 64 + lane];
        int co = nt * 16 + (lane & 15);
        float sc = g3[f * 128 + co] * rsqrtf(v3[f * 128 + co] + 1e-5f);
        float sh = b3[f * 128 + co] - m3[f * 128 + co] * sc;
        int arow = lane & 15, q8 = (lane >> 4) << 3;
        for (int mt = 0; mt < 5; ++mt) {
            ffrag C = {0.f, 0.f, 0.f, 0.f};
            int rb = mt * 16 + arow;
            for (int kc = 0; kc < 16; ++kc) {
                int row = rb + (kc >> 1);
                int ci0 = ((kc & 1) << 5) + q8;
                bfrag A = *reinterpret_cast<const bfrag*>(&smem[row * S2T_STRIDE + ci0]);
                C = __builtin_amdgcn_mfma_f32_16x16x32_bf16(A, B3[kc], C, 0, 0, 0);
            }
            int p0 = mt * 16 + ((lane >> 4) << 2);
            for (int r = 0; r < 4; ++r) {
                int p = p0 + r;
                if (p < 67)
                    smem[RB_OFF + p * RB3_STRIDE + co] = f2bt(fmaxf(C[r] * sc + sh, 0.f));
            }
        }
    }
    __syncthreads();

    // ---- pool conv3 + mean -> rep ----
    if (tid < 128) {
        int co = tid;
        float sum = bf2f(smem[RB_OFF + 0 * RB3_STRIDE + co]);
        for (int j = 1; j < 34; ++j) {
            float a0 = bf2f(smem[RB_OFF + (2 * j - 1) * RB3_STRIDE + co]);
            float a1 = bf2f(smem[RB_OFF + (2 * j) * RB3_STRIDE + co]);
            sum += fmaxf(a0, a1);
        }
        rep_p[(((size_t)f * 256) + n) * 128 + co] = sum * (1.0f / 34.0f);
    }
}

// ---- attn1 (MFMA): QKV proj + Km + scores + sparsemax + Z + rninv ----------
// one block per (pass,f,b); 256 threads (4 waves, 2 n-tiles each)
__global__ __launch_bounds__(256) void k_attn1(
    const float* __restrict__ rep, const u16* __restrict__ wqkv,
    const float* __restrict__ bq, const float* __restrict__ bk,
    const float* __restrict__ bv,
    float* __restrict__ Zn, float* __restrict__ rninv, float* __restrict__ iaw)
{
    __shared__ __align__(16) u16 repbf[16 * 136];
    __shared__ float KmL[128], ZL[128], awL[16], scoresL[16], r2L[16];
    __shared__ float spart[4][4][4];
    __shared__ float redL[4];
    int tid = threadIdx.x;
    int pass = blockIdx.x >> 7, f = (blockIdx.x >> 4) & 7, b = blockIdx.x & 15;
    const float* rp = rep + (size_t)pass * 262144 + ((size_t)f * 256 + b * 16) * 128;
    float* Zn_p = Zn + (size_t)pass * 16384;
    float* rninv_p = rninv + (size_t)pass * 2048;
    float* iaw_p = iaw + (size_t)pass * 2048;

    // stage rep -> bf16 LDS (A-layout, stride 136) + r2 row sums
    {
        int s = tid >> 4, i = tid & 15, h0 = i * 8;
        const float4* q4 = reinterpret_cast<const float4*>(rp + s * 128 + h0);
        float4 a = q4[0], c = q4[1];
        float p2 = a.x*a.x + a.y*a.y + a.z*a.z + a.w*a.w
                 + c.x*c.x + c.y*c.y + c.z*c.z + c.w*c.w;
        bfrag pk;
        pk[0] = (short)f2bt(a.x); pk[1] = (short)f2bt(a.y);
        pk[2] = (short)f2bt(a.z); pk[3] = (short)f2bt(a.w);
        pk[4] = (short)f2bt(c.x); pk[5] = (short)f2bt(c.y);
        pk[6] = (short)f2bt(c.z); pk[7] = (short)f2bt(c.w);
        *reinterpret_cast<bfrag*>(&repbf[s * 136 + h0]) = pk;
        p2 += __shfl_xor(p2, 1); p2 += __shfl_xor(p2, 2);
        p2 += __shfl_xor(p2, 4); p2 += __shfl_xor(p2, 8);
        if (i == 0) r2L[s] = p2;
    }
    __syncthreads();

    int lane = tid & 63, w = tid >> 6, arow = lane & 15, q = lane >> 4;
    bfrag A[4];
    for (int kc = 0; kc < 4; ++kc)
        A[kc] = *reinterpret_cast<const bfrag*>(&repbf[arow * 136 + kc * 32 + q * 8]);

    float qv[2][4], vvv[2][4];
    int colv[2];
    const bfrag* BB = reinterpret_cast<const bfrag*>(wqkv);
    for (int t = 0; t < 2; ++t) {
        int nt = w * 2 + t;
        ffrag cq = {0.f,0.f,0.f,0.f}, ck = {0.f,0.f,0.f,0.f}, cv = {0.f,0.f,0.f,0.f};
        for (int kc = 0; kc < 4; ++kc) {
            int fi = (nt * 4 + kc) * 64 + lane;
            bfrag Bq = BB[fi];
            bfrag Bk = BB[2048 + fi];
            bfrag Bv = BB[4096 + fi];
            cq = __builtin_amdgcn_mfma_f32_16x16x32_bf16(A[kc], Bq, cq, 0, 0, 0);
            ck = __builtin_amdgcn_mfma_f32_16x16x32_bf16(A[kc], Bk, ck, 0, 0, 0);
            cv = __builtin_amdgcn_mfma_f32_16x16x32_bf16(A[kc], Bv, cv, 0, 0, 0);
        }
        int col = nt * 16 + arow;
        colv[t] = col;
        float bqc = bq[col], bkc = bk[col], bvc = bv[col];
        float kpt = 0.f;
        for (int r = 0; r < 4; ++r) {
            qv[t][r] = eluf(cq[r] + bqc);
            vvv[t][r] = lrelu(cv[r] + bvc);
            kpt += lrelu(ck[r] + bkc);
        }
        kpt += __shfl_xor(kpt, 16);
        kpt += __shfl_xor(kpt, 32);
        if (q == 0) KmL[col] = kpt * (1.f / 16.f);
    }
    __syncthreads();

    // scores partials: ps[r] for s = q*4+r
    {
        float km0 = KmL[colv[0]], km1 = KmL[colv[1]];
        float ps[4];
        for (int r = 0; r < 4; ++r) {
            float v = qv[0][r] * km0 + qv[1][r] * km1;
            v += __shfl_xor(v, 1); v += __shfl_xor(v, 2);
            v += __shfl_xor(v, 4); v += __shfl_xor(v, 8);
            ps[r] = v;
        }
        if (arow == 0)
            for (int r = 0; r < 4; ++r) spart[w][q][r] = ps[r];
    }
    __syncthreads();
    if (tid < 16) {
        int qq = tid >> 2, rr = tid & 3;
        float sc = spart[0][qq][rr] + spart[1][qq][rr] + spart[2][qq][rr] + spart[3][qq][rr];
        scoresL[tid] = sc * 0.08838834764831845f;   // 1/sqrt(128)
        rninv_p[f * 256 + b * 16 + tid] = 1.f / fmaxf(sqrtf(r2L[tid]), 1e-12f);
    }
    __syncthreads();
    if (tid == 0) sparsemax16(scoresL, awL);
    __syncthreads();
    if (tid < 16) iaw_p[f * 256 + b * 16 + tid] = awL[tid];

    // Z = sum_s aw[s] * V[s][col]
    for (int t = 0; t < 2; ++t) {
        float zp = 0.f;
        for (int r = 0; r < 4; ++r) zp += awL[q * 4 + r] * vvv[t][r];
        zp += __shfl_xor(zp, 16);
        zp += __shfl_xor(zp, 32);
        if (q == 0) ZL[colv[t]] = zp;
    }
    __syncthreads();
    if (tid < 128) {
        float z = ZL[tid];
        float v = z * z;
        v += __shfl_xor(v, 1); v += __shfl_xor(v, 2); v += __shfl_xor(v, 4);
        v += __shfl_xor(v, 8); v += __shfl_xor(v, 16); v += __shfl_xor(v, 32);
        if (lane == 0) redL[w] = v;
    }
    __syncthreads();
    if (tid == 0) redL[2] = 1.f / fmaxf(sqrtf(redL[0] + redL[1]), 1e-12f);
    __syncthreads();
    if (tid < 128)
        Zn_p[((size_t)f * 16 + b) * 128 + tid] = ZL[tid] * redL[2];
}

// ---- inter scores + sparsemax + U + Hc + BN(feat) --------------------------
__global__ __launch_bounds__(256) void k_attn2(
    const float* __restrict__ rep, const float* __restrict__ Zn,
    const float* __restrict__ rninv, float* __restrict__ ibw,
    const float* __restrict__ g, const float* __restrict__ bb,
    const float* __restrict__ mm, const float* __restrict__ vv,
    float* __restrict__ featbn)
{
    __shared__ float ZnL[1024], sc[1024], UL[1024], nrm[8];
    int tid = threadIdx.x;
    int pass = blockIdx.x >> 4, b = blockIdx.x & 15;
    const float* rep_p = rep + (size_t)pass * 262144;
    const float* Zn_p = Zn + (size_t)pass * 16384;
    const float* rninv_p = rninv + (size_t)pass * 2048;
    float* ibw_p = ibw + (size_t)pass * 16384;

    for (int i = tid; i < 1024; i += 256) {
        int ii = i >> 7, h = i & 127;
        ZnL[i] = Zn_p[((size_t)ii * 16 + b) * 128 + h];
    }
    if (tid < 8) nrm[tid] = 0.f;
    __syncthreads();

    for (int e = tid; e < 1024; e += 256) {
        int i = e >> 7, f = (e >> 4) & 7, s = e & 15;
        const float* rr = rep_p + ((size_t)f * 256 + b * 16 + s) * 128;
        float a = 0.f;
        for (int h = 0; h < 128; ++h) a += ZnL[i * 128 + h] * rr[h];
        sc[(i * 8 + f) * 16 + s] = a * rninv_p[f * 256 + b * 16 + s];
    }
    __syncthreads();
    if (tid < 64) {
        int i = tid >> 3, f = tid & 7;
        float aw[16];
        sparsemax16(&sc[(i * 8 + f) * 16], aw);
        for (int s = 0; s < 16; ++s) {
            sc[(i * 8 + f) * 16 + s] = aw[s];
            ibw_p[(((size_t)i * 8 + f) * 16 + b) * 16 + s] = aw[s];
        }
    }
    __syncthreads();
    if (pass == 0) {
        for (int e = tid; e < 1024; e += 256) {
            int i = e >> 7, h = e & 127;
            float u = 0.f;
            for (int f = 0; f < 8; ++f) {
                const float* rr = rep_p + ((size_t)f * 256 + b * 16) * 128 + h;
                const float* aa = &sc[(i * 8 + f) * 16];
                for (int s = 0; s < 16; ++s) u += aa[s] * rr[s * 128];
            }
            UL[e] = u * 0.125f;
        }
        __syncthreads();
        for (int e = tid; e < 1024; e += 256) {
            int f = e >> 7;
            float zz = ZnL[e], uu = UL[e];
            atomicAdd(&nrm[f], zz * zz + uu * uu);
        }
        __syncthreads();
        for (int e = tid; e < 2048; e += 256) {
            int f = e >> 8, d = e & 255;
            float inv = 1.f / fmaxf(sqrtf(nrm[f]), 1e-12f);
            float val = (d < 128 ? ZnL[f * 128 + d] : UL[f * 128 + d - 128]) * inv;
            float scv = g[e] * rsqrtf(vv[e] + 1e-5f);
            featbn[b * 2048 + e] = (val - mm[e]) * scv + bb[e];
        }
    }
}

// ---- head stage 1: bn(feat)@W1+b1 -> bn2 -> lrelu -> h2ws[16][512] ---------
__global__ __launch_bounds__(256) void k_head1(
    const float* __restrict__ featbn,
    const float* __restrict__ W1, const float* __restrict__ b1,
    const float* __restrict__ g2, const float* __restrict__ bb2,
    const float* __restrict__ mm2, const float* __restrict__ vv2,
    float* __restrict__ h2ws)
{
    __shared__ float featL[2048];
    __shared__ float part[8][32];
    int tid = threadIdx.x, blk = blockIdx.x;
    int b = blk >> 4, cc = blk & 15;
    for (int i = tid; i < 2048; i += 256) featL[i] = featbn[b * 2048 + i];
    __syncthreads();
    int ci = tid & 31, ks = tid >> 5;
    int col = cc * 32 + ci;
    const float* wcol = W1 + (size_t)(ks * 256) * 512 + col;
    const float* fl = featL + ks * 256;
    float a = 0.f;
    for (int c = 0; c < 256; ++c) a += fl[c] * wcol[(size_t)c * 512];
    part[ks][ci] = a;
    __syncthreads();
    if (tid < 32) {
        int colw = cc * 32 + tid;
        float s = b1[colw];
        for (int k2 = 0; k2 < 8; ++k2) s += part[k2][tid];
        float scv = g2[colw] * rsqrtf(vv2[colw] + 1e-5f);
        float val = (s - mm2[colw]) * scv + bb2[colw];
        h2ws[b * 512 + colw] = lrelu(val);
    }
}

// ---- tail: h2 @ W2 + b2, softmax -> dout[0:160]; MMD + CE -> dout[160] -----
__global__ __launch_bounds__(256) void k_tail(
    const float* __restrict__ h2ws,
    const float* __restrict__ W2, const float* __restrict__ b2,
    const float* __restrict__ sa, const float* __restrict__ ta,
    const float* __restrict__ sb, const float* __restrict__ tb,
    const int* __restrict__ sy, float* __restrict__ dout)
{
    __shared__ float h2L[8192];
    __shared__ float lgL[160], ypL[160];
    __shared__ float sA[8], sB[8];
    int tid = threadIdx.x;
    for (int i = tid; i < 8192; i += 256) h2L[i] = h2ws[i];
    if (tid < 8) { sA[tid] = 0.f; sB[tid] = 0.f; }
    __syncthreads();
    if (tid < 160) {
        int b = tid / 10, j = tid - b * 10;
        float a = b2[j];
        const float* h = h2L + b * 512;
        for (int c = 0; c < 512; ++c) a += h[c] * W2[c * 10 + j];
        lgL[tid] = a;
    }
    __syncthreads();
    if (tid < 16) {
        int b = tid;
        float mx = lgL[b * 10];
        for (int j = 1; j < 10; ++j) mx = fmaxf(mx, lgL[b * 10 + j]);
        float sum = 0.f, ex[10];
        for (int j = 0; j < 10; ++j) { ex[j] = expf(lgL[b * 10 + j] - mx); sum += ex[j]; }
        for (int j = 0; j < 10; ++j) {
            float p = ex[j] / sum;
            ypL[b * 10 + j] = p;
            dout[b * 10 + j] = p;
        }
    }
    __syncthreads();
    if (tid < 128) {
        int f = tid >> 4, s = tid & 15;
        float d = 0.f;
        for (int b = 0; b < 16; ++b) d += sa[f * 256 + b * 16 + s] - ta[f * 256 + b * 16 + s];
        d *= (1.f / 16.f);
        atomicAdd(&sA[f], d * d);
    }
    for (int e = tid; e < 1024; e += 256) {
        int i = e >> 7, f = (e >> 4) & 7, s = e & 15;
        float d = 0.f;
        int base = ((i * 8 + f) * 16) * 16 + s;
        for (int b = 0; b < 16; ++b) d += sb[base + b * 16] - tb[base + b * 16];
        d *= (1.f / 16.f);
        atomicAdd(&sB[i], d * d);
    }
    __syncthreads();
    if (tid == 0) {
        float la = 0.f, lb = 0.f;
        for (int f = 0; f < 8; ++f) la += sqrtf(sA[f]);
        for (int i = 0; i < 8; ++i) lb += sqrtf(sB[i]);
        la *= 0.1f / 8.f;
        lb *= 0.1f / 8.f;
        float ce = 0.f;
        for (int b = 0; b < 16; ++b) {
            const float* y = ypL + b * 10;
            float mx = y[0];
            for (int j = 1; j < 10; ++j) mx = fmaxf(mx, y[j]);
            float sum = 0.f;
            for (int j = 0; j < 10; ++j) sum += expf(y[j] - mx);
            float lse = mx + logf(sum);
            ce += lse - y[sy[b]];
        }
        ce *= (1.f / 16.f);
        dout[160] = ce + la + lb;
    }
}

extern "C" void kernel_launch(void* const* d_in, const int* in_sizes, int n_in,
                              void* d_out, int out_size, void* d_ws, size_t ws_size,
                              hipStream_t stream) {
    (void)in_sizes; (void)n_in; (void)out_size; (void)ws_size;
    const float* src_x = (const float*)d_in[0];
    const int*   src_y = (const int*)d_in[1];
    const float* tgt_x = (const float*)d_in[2];
    const float *cw1 = (const float*)d_in[3], *bn1g = (const float*)d_in[4],
                *bn1b = (const float*)d_in[5], *bn1m = (const float*)d_in[6],
                *bn1v = (const float*)d_in[7];
    const float *cw2 = (const float*)d_in[8], *bn2g = (const float*)d_in[9],
                *bn2b = (const float*)d_in[10], *bn2m = (const float*)d_in[11],
                *bn2v = (const float*)d_in[12];
    const float *cw3 = (const float*)d_in[13], *bn3g = (const float*)d_in[14],
                *bn3b = (const float*)d_in[15], *bn3m = (const float*)d_in[16],
                *bn3v = (const float*)d_in[17];
    const float *Wq = (const float*)d_in[18], *bq = (const float*)d_in[19],
                *Wk = (const float*)d_in[20], *bk = (const float*)d_in[21],
                *Wv = (const float*)d_in[22], *bv = (const float*)d_in[23];
    const float *bc1g = (const float*)d_in[24], *bc1b = (const float*)d_in[25],
                *bc1m = (const float*)d_in[26], *bc1v = (const float*)d_in[27];
    const float *W1 = (const float*)d_in[28], *b1 = (const float*)d_in[29];
    const float *bc2g = (const float*)d_in[30], *bc2b = (const float*)d_in[31],
                *bc2m = (const float*)d_in[32], *bc2v = (const float*)d_in[33];
    const float *W2 = (const float*)d_in[34], *b2 = (const float*)d_in[35];

    float* ws = (float*)d_ws;
    size_t o = 0;
    float* rep    = ws + o; o += (size_t)2 * 262144;   // [pass][f,n,h]
    float* Zn     = ws + o; o += (size_t)2 * 16384;
    float* rninv  = ws + o; o += (size_t)2 * 2048;
    float* ia     = ws + o; o += (size_t)2 * 2048;
    float* ib     = ws + o; o += (size_t)2 * 16384;
    float* featbn = ws + o; o += (size_t)16 * 2048;
    float* h2ws   = ws + o; o += (size_t)16 * 512;
    u16* wpk2 = (u16*)(ws + o); o += 65536;            // 131072 u16
    u16* wpk3 = (u16*)(ws + o); o += 262144;           // 524288 u16
    u16* wqkv = (u16*)(ws + o); o += 24576;            // 49152 u16

    k_wprep<<<2752, 256, 0, stream>>>(cw2, cw3, Wq, Wk, Wv, wpk2, wpk3, wqkv);
    k_cnn<<<4096, 256, 0, stream>>>(src_x, tgt_x,
        cw1, bn1g, bn1b, bn1m, bn1v,
        bn2g, bn2b, bn2m, bn2v,
        bn3g, bn3b, bn3m, bn3v,
        wpk2, wpk3, rep);
    k_attn1<<<256, 256, 0, stream>>>(rep, wqkv, bq, bk, bv, Zn, rninv, ia);
    k_attn2<<<32, 256, 0, stream>>>(rep, Zn, rninv, ib, bc1g, bc1b, bc1m, bc1v, featbn);
    k_head1<<<256, 256, 0, stream>>>(featbn, W1, b1, bc2g, bc2b, bc2m, bc2v, h2ws);
    k_tail<<<1, 256, 0, stream>>>(h2ws, W2, b2, ia, ia + 2048, ib, ib + 16384,
                                  src_y, (float*)d_out);
}